// Round 12
// baseline (401.601 us; speedup 1.0000x reference)
//
#include <hip/hip_runtime.h>
#include <cstddef>

#define NROWS 8192
constexpr float BN_EPS = 1e-5f;

typedef __attribute__((ext_vector_type(8))) short bf16x8;
typedef __attribute__((ext_vector_type(4))) float f32x4;
typedef __attribute__((ext_vector_type(2))) float f32x2;
typedef __attribute__((ext_vector_type(4))) unsigned int u32x4;

__device__ __forceinline__ unsigned short bf16u(float f) {
    unsigned u = __float_as_uint(f);
    u += 0x7FFFu + ((u >> 16) & 1u);
    return (unsigned short)(u >> 16);
}
__device__ __forceinline__ unsigned bf16pk(float x, float y) {
    return (unsigned)bf16u(x) | ((unsigned)bf16u(y) << 16);
}

// ---- workspace layout (float offsets) ----
constexpr size_t OFF_P   = 0;                                   // 16*8192*32 max
constexpr size_t OFF_YP  = OFF_P   + (size_t)16 * NROWS * 32;   // 8192*32 ushort
constexpr size_t OFF_SLP = OFF_YP  + (size_t)NROWS * 32 / 2;    // 8192*32 ushort
constexpr size_t OFF_U   = OFF_SLP + (size_t)NROWS * 32 / 2;    // (unused)
constexpr size_t OFF_SL  = OFF_U   + (size_t)NROWS * 16;        // 8192*20 f32
constexpr size_t OFF_ST1 = OFF_SL  + (size_t)NROWS * 20;        // 32
constexpr size_t OFF_ST2 = OFF_ST1 + 32;                        // 32
constexpr size_t OFF_HSM = OFF_ST2 + 32;                        // 160
constexpr size_t OFF_AG  = OFF_HSM + 160;                       // 400
constexpr size_t OFF_CTR = OFF_AG  + 400;                       // 8 uint
constexpr int    NSMALL  = 32 + 32 + 160 + 400 + 8;             // 632 floats
constexpr size_t OFF_END_SMALL = OFF_CTR + 8;
constexpr size_t OFF_ADJB = (OFF_END_SMALL + 15) & ~(size_t)15; // 8192*8192 bf16 (packed)
constexpr size_t NEED_FULL_BYTES = (OFF_ADJB + (size_t)NROWS * NROWS / 2) * 4;

// ============================================================
// Packed-fragment ADJP layout, in 16-B units (8 bf16):
//   unit = ((kc*64 + rb)*4 + wv)*2048 + s*128 + m*64 + lane
// lane = rA + 16*khi holds adj[rb*128+wv*32+m*16+rA, kc*512+s*32+khi*8 ..+7]
// LDS swizzle involution: u ^= ((u>>4)&3) ^ (((u>>7)&1)<<2)
// Grid-wide handoff pattern (proven in red_bn since r8): producers
// store -> __threadfence -> __syncthreads -> thread0 atomicAdd(ctr);
// workers spin (agent scope) -> __threadfence -> __syncthreads -> read.
// All grids <= co-resident capacity (4 blocks/CU x 256 CU = 1024).
// ============================================================

// ---- fused: fp32 adj -> packed bf16 ADJP AND pass-1 spmm ----
// Single 32 KB LDS buffer. r8 dbuf (occupancy cliff) and r10 subtile
// pipeline (narrow bursts) both regressed — plain loop, deeper unroll.
__global__ __launch_bounds__(256, 4)
void k_conv_spmm(const float* __restrict__ adjf, unsigned short* __restrict__ adjp,
                 const unsigned short* __restrict__ ypu, float* __restrict__ P)
{
    __shared__ unsigned short lds[16384];   // 32 KB = 2048 16-B units
    const int bid = blockIdx.x;
    const int rb = bid & 63, kc = bid >> 6;
    const int t = threadIdx.x, lane = t & 63, wv = t >> 6;
    const int row0 = rb * 128 + wv * 32;
    const int s_q = lane >> 4;
    const int khi = (lane >> 2) & 3;
    const int el2 = (lane & 3) * 2;
    const bf16x8* ap = (const bf16x8*)lds;
    const bf16x8* yp = (const bf16x8*)ypu;
    const size_t blockbase = (size_t)(kc * 64 + rb) * 8192;   // 16-B units

    f32x4 acc0 = (f32x4){0.f,0.f,0.f,0.f}, acc1 = (f32x4){0.f,0.f,0.f,0.f};

    for (int q = 0; q < 4; ++q) {
        const int kbase = kc * 512 + q * 128;
        __syncthreads();
#pragma unroll 16
        for (int rr = 0; rr < 32; ++rr) {
            const f32x2 v = *(const f32x2*)(adjf + (size_t)(row0 + rr) * NROWS + kbase + lane * 2);
            const int m = rr >> 4, rA = rr & 15;
            int u = ((wv * 4 + s_q) * 2 + m) * 64 + rA + 16 * khi;
            u ^= ((u >> 4) & 3) ^ (((u >> 7) & 1) << 2);
            *(unsigned*)&lds[u * 8 + el2] = bf16pk(v.x, v.y);
        }
        __syncthreads();
#pragma unroll
        for (int i = 0; i < 8; ++i) {
            const int flat = i * 256 + t;
            const int phys = flat ^ ((flat >> 4) & 3) ^ (((flat >> 7) & 1) << 2);
            const u32x4 d = *(const u32x4*)&lds[phys * 8];
            const int wvd = flat >> 9;
            const size_t gu = blockbase + (size_t)wvd * 2048 + (size_t)q * 512 + (flat & 511);
            *(u32x4*)(adjp + gu * 8) = d;
        }
#pragma unroll
        for (int sq = 0; sq < 4; ++sq) {
            int L0 = ((wv * 4 + sq) * 2 + 0) * 64 + lane;
            int L1 = L0 + 64;
            L0 ^= ((L0 >> 4) & 3) ^ (((L0 >> 7) & 1) << 2);
            L1 ^= ((L1 >> 4) & 3) ^ (((L1 >> 7) & 1) << 2);
            const bf16x8 a0 = ap[L0];
            const bf16x8 a1 = ap[L1];
            const bf16x8 b0 = yp[((size_t)(kc * 16 + q * 4 + sq)) * 64 + lane];
            acc0 = __builtin_amdgcn_mfma_f32_16x16x32_bf16(a0, b0, acc0, 0, 0, 0);
            acc1 = __builtin_amdgcn_mfma_f32_16x16x32_bf16(a1, b0, acc1, 0, 0, 0);
        }
    }

    float* Pk = P + ((size_t)kc * NROWS + row0) * 16;
    const int drow = (lane >> 4) * 4;
    const int dcol = lane & 15;
#pragma unroll
    for (int r = 0; r < 4; ++r) {
        Pk[(size_t)(drow + r) * 16 + dcol]      = acc0[r];
        Pk[(size_t)(16 + drow + r) * 16 + dcol] = acc1[r];
    }
}

// ---- pass 2 fused: spmm(NT=1,CO=16,splitk8) + grid-spin + red_bn epilogue ----
// grid MUST be 512; workers = first 64 bids. ctrs[0]: 512-spin, ctrs[1]: 64-spin.
__global__ __launch_bounds__(256, 4)
void k_spmm_bn(const unsigned short* __restrict__ adjp, unsigned short* yp_io,
               float* __restrict__ P, const float* __restrict__ bias,
               const float* __restrict__ g, const float* __restrict__ bt,
               const float* __restrict__ Wa, const float* __restrict__ Wb,
               float* __restrict__ stats, unsigned int* __restrict__ ctrs)
{
    const int rb   = blockIdx.x & 63;
    const int kc2  = blockIdx.x >> 6;
    const int lane = threadIdx.x & 63;
    const int wv   = threadIdx.x >> 6;
    const int row0 = rb * 128 + wv * 32;
    const bf16x8* ap = (const bf16x8*)adjp;
    const bf16x8* yp = (const bf16x8*)yp_io;
    const size_t wbase0 = ((size_t)((kc2 * 2 + 0) * 64 + rb) * 4 + wv) * 2048;
    const size_t wbase1 = ((size_t)((kc2 * 2 + 1) * 64 + rb) * 4 + wv) * 2048;

    f32x4 acc0 = (f32x4){0.f,0.f,0.f,0.f}, acc1 = (f32x4){0.f,0.f,0.f,0.f};
    auto LA = [&](int m, int s) -> bf16x8 {
        const size_t wb = (s < 16) ? wbase0 : wbase1;
        return ap[wb + (size_t)(s & 15) * 128 + m * 64 + lane];
    };
    auto LB = [&](int s) -> bf16x8 {
        return yp[((size_t)(kc2 * 32 + s)) * 64 + lane];
    };
    bf16x8 a0 = LA(0, 0), a1 = LA(1, 0), b0 = LB(0);
#pragma unroll
    for (int s = 0; s < 32; ++s) {
        bf16x8 na0, na1, nb0;
        if (s < 31) { na0 = LA(0, s + 1); na1 = LA(1, s + 1); nb0 = LB(s + 1); }
        acc0 = __builtin_amdgcn_mfma_f32_16x16x32_bf16(a0, b0, acc0, 0, 0, 0);
        acc1 = __builtin_amdgcn_mfma_f32_16x16x32_bf16(a1, b0, acc1, 0, 0, 0);
        if (s < 31) { a0 = na0; a1 = na1; b0 = nb0; }
    }
    {
        float* Pk = P + ((size_t)kc2 * NROWS + row0) * 16;
        const int drow = (lane >> 4) * 4, dcol = lane & 15;
#pragma unroll
        for (int r = 0; r < 4; ++r) {
            Pk[(size_t)(drow + r) * 16 + dcol]      = acc0[r];
            Pk[(size_t)(16 + drow + r) * 16 + dcol] = acc1[r];
        }
    }
    // handoff
    __threadfence();
    __syncthreads();
    if (threadIdx.x == 0) atomicAdd(&ctrs[0], 1u);
    if (blockIdx.x >= 64) return;
    if (threadIdx.x == 0) {
        while (__hip_atomic_load(&ctrs[0], __ATOMIC_RELAXED, __HIP_MEMORY_SCOPE_AGENT) < 512u) {}
        __threadfence();
    }
    __syncthreads();

    // ---- red_bn epilogue: KCN=8, COA=8, COB=20, NTO=2 ----
    const int t = threadIdx.x, col = t & 15, rg = t >> 4;
    const int rbase = blockIdx.x * 128;
    float u[8];
    float s = 0.f, ss = 0.f;
#pragma unroll
    for (int i = 0; i < 8; ++i) {
        const int r = rbase + rg + i * 16;
        float v = bias[col];
#pragma unroll
        for (int kc = 0; kc < 8; ++kc)
            v += P[((size_t)kc * NROWS + r) * 16 + col];
        v = fmaxf(v, 0.f);
        u[i] = v; s += v; ss += v * v;
    }
    __shared__ float ls[16][17], lss[16][17];
    __shared__ float hb[128][17];
    __shared__ float scb[16], shb[16];
    ls[rg][col] = s; lss[rg][col] = ss;
    __syncthreads();
    if (t < 16) {
        float a = 0.f, b = 0.f;
        for (int gg = 0; gg < 16; ++gg) { a += ls[gg][t]; b += lss[gg][t]; }
        atomicAdd(&stats[t], a);
        atomicAdd(&stats[16 + t], b);
    }
    __syncthreads();
    if (t == 0) {
        __threadfence();
        atomicAdd(&ctrs[1], 1u);
        while (__hip_atomic_load(&ctrs[1], __ATOMIC_RELAXED, __HIP_MEMORY_SCOPE_AGENT) < 64u) {}
        __threadfence();
    }
    __syncthreads();
    if (t < 16) {
        const float sm  = atomicAdd(&stats[t], 0.f);
        const float sq  = atomicAdd(&stats[16 + t], 0.f);
        const float m   = sm * (1.f / NROWS);
        const float var = sq * (1.f / NROWS) - m * m;
        const float sc  = g[t] * rsqrtf(var + BN_EPS);
        scb[t] = sc; shb[t] = bt[t] - m * sc;
    }
    __syncthreads();
#pragma unroll
    for (int i = 0; i < 8; ++i)
        hb[rg + i * 16][col] = fmaf(u[i], scb[col], shb[col]);
    __syncthreads();
    const int lrow = t >> 1;
    const int jrow = rbase + lrow;
    const int kb = jrow >> 5, lhi = ((jrow & 31) >> 3) << 4, idx = jrow & 7;
    auto slot = [&](int c) -> size_t {
        return ((size_t)(kb * 2 + (c >> 4)) * 64 + (lhi | (c & 15))) * 8 + idx;
    };
    float h[16];
#pragma unroll
    for (int k = 0; k < 16; ++k) h[k] = hb[lrow][k];
    const int c0 = (t & 1) * 16;
#pragma unroll
    for (int cc = 0; cc < 16; ++cc) {
        const int c = c0 + cc;
        float a = 0.f;
        if (c < 8) {
#pragma unroll
            for (int k = 0; k < 16; ++k) a = fmaf(h[k], Wa[k * 8 + c], a);
        } else if (c < 28) {
#pragma unroll
            for (int k = 0; k < 16; ++k) a = fmaf(h[k], Wb[k * 20 + (c - 8)], a);
        }
        yp_io[slot(c)] = (c < 28) ? bf16u(a) : (unsigned short)0;
    }
}

// ---- pass 3 fused: spmm(NT=2,CO=28) + grid-spin + fin3 epilogue (32 workers) ----
__global__ __launch_bounds__(256, 4)
void k_spmm_fin3(const unsigned short* __restrict__ adjp,
                 const unsigned short* __restrict__ ypu, float* __restrict__ P,
                 const float* __restrict__ be1, const float* __restrict__ bp1,
                 float* __restrict__ sl, unsigned short* __restrict__ slp,
                 float* __restrict__ hsm, unsigned int* __restrict__ ctr)
{
    const int rb   = blockIdx.x & 63;
    const int kc2  = blockIdx.x >> 6;
    const int lane = threadIdx.x & 63;
    const int wv   = threadIdx.x >> 6;
    const int row0 = rb * 128 + wv * 32;
    const bf16x8* ap = (const bf16x8*)adjp;
    const bf16x8* yp = (const bf16x8*)ypu;
    const size_t wbase0 = ((size_t)((kc2 * 2 + 0) * 64 + rb) * 4 + wv) * 2048;
    const size_t wbase1 = ((size_t)((kc2 * 2 + 1) * 64 + rb) * 4 + wv) * 2048;

    f32x4 acc[2][2];
#pragma unroll
    for (int m = 0; m < 2; ++m)
#pragma unroll
        for (int n = 0; n < 2; ++n) acc[m][n] = (f32x4){0.f, 0.f, 0.f, 0.f};
    auto LA = [&](int m, int s) -> bf16x8 {
        const size_t wb = (s < 16) ? wbase0 : wbase1;
        return ap[wb + (size_t)(s & 15) * 128 + m * 64 + lane];
    };
    auto LB = [&](int n, int s) -> bf16x8 {
        return yp[((size_t)((kc2 * 32 + s) * 2 + n)) * 64 + lane];
    };
    bf16x8 a0 = LA(0, 0), a1 = LA(1, 0), b0 = LB(0, 0), b1 = LB(1, 0);
#pragma unroll
    for (int s = 0; s < 32; ++s) {
        bf16x8 na0, na1, nb0, nb1;
        if (s < 31) { na0 = LA(0, s+1); na1 = LA(1, s+1); nb0 = LB(0, s+1); nb1 = LB(1, s+1); }
        acc[0][0] = __builtin_amdgcn_mfma_f32_16x16x32_bf16(a0, b0, acc[0][0], 0, 0, 0);
        acc[1][0] = __builtin_amdgcn_mfma_f32_16x16x32_bf16(a1, b0, acc[1][0], 0, 0, 0);
        acc[0][1] = __builtin_amdgcn_mfma_f32_16x16x32_bf16(a0, b1, acc[0][1], 0, 0, 0);
        acc[1][1] = __builtin_amdgcn_mfma_f32_16x16x32_bf16(a1, b1, acc[1][1], 0, 0, 0);
        if (s < 31) { a0 = na0; a1 = na1; b0 = nb0; b1 = nb1; }
    }
    {
        float* Pk = P + ((size_t)kc2 * NROWS + row0) * 32;
        const int drow = (lane >> 4) * 4, dcol = lane & 15;
#pragma unroll
        for (int m = 0; m < 2; ++m)
#pragma unroll
            for (int n = 0; n < 2; ++n)
#pragma unroll
                for (int r = 0; r < 4; ++r)
                    if (n * 16 + dcol < 28)
                        Pk[(size_t)(m * 16 + drow + r) * 32 + n * 16 + dcol] = acc[m][n][r];
    }
    __threadfence();
    __syncthreads();
    if (threadIdx.x == 0) atomicAdd(ctr, 1u);
    if (blockIdx.x >= 32) return;
    if (threadIdx.x == 0) {
        while (__hip_atomic_load(ctr, __ATOMIC_RELAXED, __HIP_MEMORY_SCOPE_AGENT) < 512u) {}
        __threadfence();
    }
    __syncthreads();

    // ---- fin3 epilogue: KCN=8, 256 rows per worker ----
    __shared__ float szl[256 * 8];
    __shared__ float ssl[256 * 20];
    const int t = threadIdx.x;
    const int row = blockIdx.x * 256 + t;
    float s3[28];
#pragma unroll
    for (int c = 0; c < 28; ++c) s3[c] = 0.f;
#pragma unroll
    for (int kc = 0; kc < 8; ++kc) {
        const float* pr = &P[((size_t)kc * NROWS + row) * 32];
#pragma unroll
        for (int q = 0; q < 7; ++q) {
            const f32x4 v = *(const f32x4*)(pr + q * 4);
            s3[q * 4 + 0] += v.x; s3[q * 4 + 1] += v.y;
            s3[q * 4 + 2] += v.z; s3[q * 4 + 3] += v.w;
        }
    }
#pragma unroll
    for (int k = 0; k < 8; ++k) szl[t * 8 + k] = s3[k] + be1[k];
    float s[20];
    float mx = -1e30f;
#pragma unroll
    for (int k = 0; k < 20; ++k) {
        s[k] = s3[8 + k] + bp1[k];
        mx = fmaxf(mx, s[k]);
    }
    float se = 0.f;
#pragma unroll
    for (int k = 0; k < 20; ++k) { s[k] = expf(s[k] - mx); se += s[k]; }
    const float inv = 1.f / se;
    const int kb = row >> 5, lhi = ((row & 31) >> 3) << 4, idx = row & 7;
    auto slot = [&](int c) -> size_t {
        return ((size_t)(kb * 2 + (c >> 4)) * 64 + (lhi | (c & 15))) * 8 + idx;
    };
#pragma unroll
    for (int k = 0; k < 20; ++k) {
        s[k] *= inv;
        sl[(size_t)row * 20 + k] = s[k];
        ssl[t * 20 + k] = s[k];
        slp[slot(k)] = bf16u(s[k]);
    }
#pragma unroll
    for (int c = 20; c < 32; ++c) slp[slot(c)] = 0;
    __syncthreads();
    if (t < 160) {
        const int p = t >> 3, q = t & 7;
        float a = 0.f;
        for (int r = 0; r < 256; ++r) a = fmaf(ssl[r * 20 + p], szl[r * 8 + q], a);
        atomicAdd(&hsm[t], a);
    }
}

// ---- pass 4 fused: spmm(NT=2,CO=20) + grid-spin + fin4 epilogue (32 workers) ----
__global__ __launch_bounds__(256, 4)
void k_spmm_fin4(const unsigned short* __restrict__ adjp,
                 const unsigned short* __restrict__ slpu, float* __restrict__ P,
                 const float* __restrict__ sl, float* __restrict__ a_g,
                 unsigned int* __restrict__ ctr)
{
    const int rb   = blockIdx.x & 63;
    const int kc2  = blockIdx.x >> 6;
    const int lane = threadIdx.x & 63;
    const int wv   = threadIdx.x >> 6;
    const int row0 = rb * 128 + wv * 32;
    const bf16x8* ap = (const bf16x8*)adjp;
    const bf16x8* yp = (const bf16x8*)slpu;
    const size_t wbase0 = ((size_t)((kc2 * 2 + 0) * 64 + rb) * 4 + wv) * 2048;
    const size_t wbase1 = ((size_t)((kc2 * 2 + 1) * 64 + rb) * 4 + wv) * 2048;

    f32x4 acc[2][2];
#pragma unroll
    for (int m = 0; m < 2; ++m)
#pragma unroll
        for (int n = 0; n < 2; ++n) acc[m][n] = (f32x4){0.f, 0.f, 0.f, 0.f};
    auto LA = [&](int m, int s) -> bf16x8 {
        const size_t wb = (s < 16) ? wbase0 : wbase1;
        return ap[wb + (size_t)(s & 15) * 128 + m * 64 + lane];
    };
    auto LB = [&](int n, int s) -> bf16x8 {
        return yp[((size_t)((kc2 * 32 + s) * 2 + n)) * 64 + lane];
    };
    bf16x8 a0 = LA(0, 0), a1 = LA(1, 0), b0 = LB(0, 0), b1 = LB(1, 0);
#pragma unroll
    for (int s = 0; s < 32; ++s) {
        bf16x8 na0, na1, nb0, nb1;
        if (s < 31) { na0 = LA(0, s+1); na1 = LA(1, s+1); nb0 = LB(0, s+1); nb1 = LB(1, s+1); }
        acc[0][0] = __builtin_amdgcn_mfma_f32_16x16x32_bf16(a0, b0, acc[0][0], 0, 0, 0);
        acc[1][0] = __builtin_amdgcn_mfma_f32_16x16x32_bf16(a1, b0, acc[1][0], 0, 0, 0);
        acc[0][1] = __builtin_amdgcn_mfma_f32_16x16x32_bf16(a0, b1, acc[0][1], 0, 0, 0);
        acc[1][1] = __builtin_amdgcn_mfma_f32_16x16x32_bf16(a1, b1, acc[1][1], 0, 0, 0);
        if (s < 31) { a0 = na0; a1 = na1; b0 = nb0; b1 = nb1; }
    }
    {
        float* Pk = P + ((size_t)kc2 * NROWS + row0) * 32;
        const int drow = (lane >> 4) * 4, dcol = lane & 15;
#pragma unroll
        for (int m = 0; m < 2; ++m)
#pragma unroll
            for (int n = 0; n < 2; ++n)
#pragma unroll
                for (int r = 0; r < 4; ++r)
                    if (n * 16 + dcol < 20)
                        Pk[(size_t)(m * 16 + drow + r) * 32 + n * 16 + dcol] = acc[m][n][r];
    }
    __threadfence();
    __syncthreads();
    if (threadIdx.x == 0) atomicAdd(ctr, 1u);
    if (blockIdx.x >= 32) return;
    if (threadIdx.x == 0) {
        while (__hip_atomic_load(ctr, __ATOMIC_RELAXED, __HIP_MEMORY_SCOPE_AGENT) < 512u) {}
        __threadfence();
    }
    __syncthreads();

    // ---- fin4 epilogue: KCN=8, 256 rows per worker ----
    __shared__ float stt[256 * 20];
    __shared__ float ssl[256 * 20];
    const int t = threadIdx.x;
    const int row = blockIdx.x * 256 + t;
    float t4[20];
#pragma unroll
    for (int c = 0; c < 20; ++c) t4[c] = 0.f;
#pragma unroll
    for (int kc = 0; kc < 8; ++kc) {
        const float* pr = &P[((size_t)kc * NROWS + row) * 32];
#pragma unroll
        for (int q = 0; q < 5; ++q) {
            const f32x4 v = *(const f32x4*)(pr + q * 4);
            t4[q * 4 + 0] += v.x; t4[q * 4 + 1] += v.y;
            t4[q * 4 + 2] += v.z; t4[q * 4 + 3] += v.w;
        }
    }
#pragma unroll
    for (int c = 0; c < 20; ++c) {
        stt[t * 20 + c] = t4[c];
        ssl[t * 20 + c] = sl[(size_t)row * 20 + c];
    }
    __syncthreads();
    for (int pair = t; pair < 400; pair += 256) {
        const int p = pair / 20, q = pair % 20;
        float a = 0.f;
        for (int r = 0; r < 256; ++r) a = fmaf(ssl[r * 20 + p], stt[r * 20 + q], a);
        atomicAdd(&a_g[pair], a);
    }
}

// ---- fallback spmm reading fp32 adj directly (non-FULL only, split-16) ----
template<int NT, int CO>
__global__ __launch_bounds__(256)
void k_spmm_f32(const float* __restrict__ adjf,
                const unsigned short* __restrict__ ypu, float* __restrict__ P)
{
    constexpr int CP = NT * 16;
    const int rb   = blockIdx.x & 63;
    const int kc   = blockIdx.x >> 6;
    const int lane = threadIdx.x & 63;
    const int wv   = threadIdx.x >> 6;
    const int row0 = rb * 128 + wv * 32;
    const int k0   = kc * 512;
    const int rA   = lane & 15;
    const int kA   = (lane >> 4) * 8;
    const bf16x8* yp = (const bf16x8*)ypu;

    f32x4 acc[2][NT];
#pragma unroll
    for (int m = 0; m < 2; ++m)
#pragma unroll
        for (int n = 0; n < NT; ++n) acc[m][n] = (f32x4){0.f, 0.f, 0.f, 0.f};

    const size_t offA0 = (size_t)(row0 + rA) * NROWS + k0 + kA;
    const size_t offA1 = offA0 + (size_t)16 * NROWS;

    auto LA = [&](int m, int s) -> bf16x8 {
        const size_t o = (m ? offA1 : offA0) + (size_t)s * 32;
        const f32x4 u = *(const f32x4*)(adjf + o);
        const f32x4 v = *(const f32x4*)(adjf + o + 4);
        bf16x8 tt;
        tt[0] = (short)bf16u(u.x); tt[1] = (short)bf16u(u.y);
        tt[2] = (short)bf16u(u.z); tt[3] = (short)bf16u(u.w);
        tt[4] = (short)bf16u(v.x); tt[5] = (short)bf16u(v.y);
        tt[6] = (short)bf16u(v.z); tt[7] = (short)bf16u(v.w);
        return tt;
    };
    auto LB = [&](int n, int s) -> bf16x8 {
        return yp[((size_t)((kc * 16 + s) * NT + n)) * 64 + lane];
    };

    bf16x8 a0 = LA(0, 0), a1 = LA(1, 0);
    bf16x8 b0 = LB(0, 0), b1;
    if constexpr (NT == 2) b1 = LB(1, 0);

#pragma unroll
    for (int s = 0; s < 16; ++s) {
        bf16x8 na0, na1, nb0, nb1;
        if (s < 15) {
            na0 = LA(0, s + 1); na1 = LA(1, s + 1);
            nb0 = LB(0, s + 1);
            if constexpr (NT == 2) nb1 = LB(1, s + 1);
        }
        acc[0][0] = __builtin_amdgcn_mfma_f32_16x16x32_bf16(a0, b0, acc[0][0], 0, 0, 0);
        acc[1][0] = __builtin_amdgcn_mfma_f32_16x16x32_bf16(a1, b0, acc[1][0], 0, 0, 0);
        if constexpr (NT == 2) {
            acc[0][1] = __builtin_amdgcn_mfma_f32_16x16x32_bf16(a0, b1, acc[0][1], 0, 0, 0);
            acc[1][1] = __builtin_amdgcn_mfma_f32_16x16x32_bf16(a1, b1, acc[1][1], 0, 0, 0);
        }
        if (s < 15) { a0 = na0; a1 = na1; b0 = nb0; if constexpr (NT == 2) b1 = nb1; }
    }

    float* Pk = P + ((size_t)kc * NROWS + row0) * CP;
    const int drow = (lane >> 4) * 4;
    const int dcol = lane & 15;
#pragma unroll
    for (int m = 0; m < 2; ++m)
#pragma unroll
        for (int n = 0; n < NT; ++n)
            if (n * 16 + 0 < CO)
#pragma unroll
                for (int r = 0; r < 4; ++r)
                    if (n * 16 + dcol < CO)
                        Pk[(size_t)(m * 16 + drow + r) * CP + n * 16 + dcol] = acc[m][n][r];
}

// ---- y1 = x @ W1 (packed B-frag) + zero small accumulators (block 0) ----
__global__ __launch_bounds__(256)
void k_y1_pack(const float* __restrict__ x, const float* __restrict__ W1,
               unsigned short* __restrict__ yp, float* __restrict__ zsmall)
{
    if (blockIdx.x == 0) {
        for (int i = threadIdx.x; i < NSMALL; i += 256) zsmall[i] = 0.f;
    }
    const int j = blockIdx.x * 256 + threadIdx.x;
    float xr[18];
#pragma unroll
    for (int d = 0; d < 18; ++d) xr[d] = x[j * 18 + d];
    const int kb = j >> 5, lhi = ((j & 31) >> 3) << 4, idx = j & 7;
#pragma unroll
    for (int c = 0; c < 16; ++c) {
        float a = 0.f;
#pragma unroll
        for (int d = 0; d < 18; ++d) a = fmaf(xr[d], W1[d * 16 + c], a);
        yp[((size_t)kb * 64 + (lhi | c)) * 8 + idx] = bf16u(a);
    }
}

// ---- standalone red_bn (pass 1 + non-FULL): grid MUST be 64 ----
template<int KCN, int COA, int COB, int NTO>
__global__ __launch_bounds__(256)
void k_red_bn(const float* __restrict__ P, const float* __restrict__ bias,
              const float* __restrict__ g, const float* __restrict__ bt,
              const float* __restrict__ Wa, const float* __restrict__ Wb,
              unsigned short* __restrict__ yp, float* __restrict__ stats,
              unsigned int* __restrict__ ctr)
{
    const int t = threadIdx.x, col = t & 15, rg = t >> 4;
    const int rbase = blockIdx.x * 128;
    float u[8];
    float s = 0.f, ss = 0.f;
#pragma unroll
    for (int i = 0; i < 8; ++i) {
        const int r = rbase + rg + i * 16;
        float v = bias[col];
#pragma unroll
        for (int kc = 0; kc < KCN; ++kc)
            v += P[((size_t)kc * NROWS + r) * 16 + col];
        v = fmaxf(v, 0.f);
        u[i] = v; s += v; ss += v * v;
    }
    __shared__ float ls[16][17], lss[16][17];
    __shared__ float hb[128][17];
    __shared__ float scb[16], shb[16];
    ls[rg][col] = s; lss[rg][col] = ss;
    __syncthreads();
    if (t < 16) {
        float a = 0.f, b = 0.f;
        for (int gg = 0; gg < 16; ++gg) { a += ls[gg][t]; b += lss[gg][t]; }
        atomicAdd(&stats[t], a);
        atomicAdd(&stats[16 + t], b);
    }
    __syncthreads();
    if (t == 0) {
        __threadfence();
        atomicAdd(ctr, 1u);
        while (__hip_atomic_load(ctr, __ATOMIC_RELAXED, __HIP_MEMORY_SCOPE_AGENT) < 64u) {}
        __threadfence();
    }
    __syncthreads();
    if (t < 16) {
        const float sm  = atomicAdd(&stats[t], 0.f);
        const float sq  = atomicAdd(&stats[16 + t], 0.f);
        const float m   = sm * (1.f / NROWS);
        const float var = sq * (1.f / NROWS) - m * m;
        const float sc  = g[t] * rsqrtf(var + BN_EPS);
        scb[t] = sc; shb[t] = bt[t] - m * sc;
    }
    __syncthreads();
#pragma unroll
    for (int i = 0; i < 8; ++i)
        hb[rg + i * 16][col] = fmaf(u[i], scb[col], shb[col]);
    __syncthreads();
    constexpr int CO = COA + COB;
    const int lrow = t >> 1;
    const int jrow = rbase + lrow;
    const int kb = jrow >> 5, lhi = ((jrow & 31) >> 3) << 4, idx = jrow & 7;
    auto slot = [&](int c) -> size_t {
        return ((size_t)(kb * NTO + (c >> 4)) * 64 + (lhi | (c & 15))) * 8 + idx;
    };
    float h[16];
#pragma unroll
    for (int k = 0; k < 16; ++k) h[k] = hb[lrow][k];
    const int c0 = (t & 1) * ((NTO * 16) / 2);
#pragma unroll
    for (int cc = 0; cc < (NTO * 16) / 2; ++cc) {
        const int c = c0 + cc;
        float a = 0.f;
        if (c < COA) {
#pragma unroll
            for (int k = 0; k < 16; ++k) a = fmaf(h[k], Wa[k * COA + c], a);
        } else if (c < CO) {
#pragma unroll
            for (int k = 0; k < 16; ++k) a = fmaf(h[k], Wb[k * COB + (c - COA)], a);
        }
        yp[slot(c)] = (c < CO) ? bf16u(a) : (unsigned short)0;
    }
}

// ---- standalone fin3/fin4 (non-FULL fallback) ----
template<int KCN>
__global__ __launch_bounds__(256)
void k_red_fin3(const float* __restrict__ P, const float* __restrict__ be1,
                const float* __restrict__ bp1, float* __restrict__ sl,
                unsigned short* __restrict__ slp, float* __restrict__ hsm)
{
    __shared__ float szl[256 * 8];
    __shared__ float ssl[256 * 20];
    const int t = threadIdx.x;
    const int row = blockIdx.x * 256 + t;
    float s3[28];
#pragma unroll
    for (int c = 0; c < 28; ++c) s3[c] = 0.f;
#pragma unroll
    for (int kc = 0; kc < KCN; ++kc) {
        const float* pr = &P[((size_t)kc * NROWS + row) * 32];
#pragma unroll
        for (int q = 0; q < 7; ++q) {
            const f32x4 v = *(const f32x4*)(pr + q * 4);
            s3[q * 4 + 0] += v.x; s3[q * 4 + 1] += v.y;
            s3[q * 4 + 2] += v.z; s3[q * 4 + 3] += v.w;
        }
    }
#pragma unroll
    for (int k = 0; k < 8; ++k) szl[t * 8 + k] = s3[k] + be1[k];
    float s[20];
    float mx = -1e30f;
#pragma unroll
    for (int k = 0; k < 20; ++k) {
        s[k] = s3[8 + k] + bp1[k];
        mx = fmaxf(mx, s[k]);
    }
    float se = 0.f;
#pragma unroll
    for (int k = 0; k < 20; ++k) { s[k] = expf(s[k] - mx); se += s[k]; }
    const float inv = 1.f / se;
    const int kb = row >> 5, lhi = ((row & 31) >> 3) << 4, idx = row & 7;
    auto slot = [&](int c) -> size_t {
        return ((size_t)(kb * 2 + (c >> 4)) * 64 + (lhi | (c & 15))) * 8 + idx;
    };
#pragma unroll
    for (int k = 0; k < 20; ++k) {
        s[k] *= inv;
        sl[(size_t)row * 20 + k] = s[k];
        ssl[t * 20 + k] = s[k];
        slp[slot(k)] = bf16u(s[k]);
    }
#pragma unroll
    for (int c = 20; c < 32; ++c) slp[slot(c)] = 0;
    __syncthreads();
    if (t < 160) {
        const int p = t >> 3, q = t & 7;
        float a = 0.f;
        for (int r = 0; r < 256; ++r) a = fmaf(ssl[r * 20 + p], szl[r * 8 + q], a);
        atomicAdd(&hsm[t], a);
    }
}

template<int KCN>
__global__ __launch_bounds__(256)
void k_red_fin4(const float* __restrict__ P, const float* __restrict__ sl,
                float* __restrict__ a_g)
{
    __shared__ float stt[256 * 20];
    __shared__ float ssl[256 * 20];
    const int t = threadIdx.x;
    const int row = blockIdx.x * 256 + t;
    float t4[20];
#pragma unroll
    for (int c = 0; c < 20; ++c) t4[c] = 0.f;
#pragma unroll
    for (int kc = 0; kc < KCN; ++kc) {
        const float* pr = &P[((size_t)kc * NROWS + row) * 32];
#pragma unroll
        for (int q = 0; q < 5; ++q) {
            const f32x4 v = *(const f32x4*)(pr + q * 4);
            t4[q * 4 + 0] += v.x; t4[q * 4 + 1] += v.y;
            t4[q * 4 + 2] += v.z; t4[q * 4 + 3] += v.w;
        }
    }
#pragma unroll
    for (int c = 0; c < 20; ++c) {
        stt[t * 20 + c] = t4[c];
        ssl[t * 20 + c] = sl[(size_t)row * 20 + c];
    }
    __syncthreads();
    for (int pair = t; pair < 400; pair += 256) {
        const int p = pair / 20, q = pair % 20;
        float a = 0.f;
        for (int r = 0; r < 256; ++r) a = fmaf(ssl[r * 20 + p], stt[r * 20 + q], a);
        atomicAdd(&a_g[pair], a);
    }
}

// ---- tiny final stage ----
__global__ __launch_bounds__(256)
void k_final(const float* __restrict__ hsm, const float* __restrict__ a_g,
             const float* __restrict__ W3, const float* __restrict__ b3,
             const float* __restrict__ g3, const float* __restrict__ bt3,
             const float* __restrict__ We2, const float* __restrict__ be2,
             float* __restrict__ out)
{
    __shared__ float m1[160], qb[160], hb[160], sc[8], sh[8];
    const int t = threadIdx.x;
    const int p = t >> 3, k = t & 7;
    if (t < 160) {
        float a = 0.f;
        for (int j = 0; j < 8; ++j) a = fmaf(hsm[p * 8 + j], W3[j * 8 + k], a);
        m1[t] = a;
    }
    __syncthreads();
    if (t < 160) {
        float a = b3[k];
        for (int j = 0; j < 20; ++j) a = fmaf(a_g[p * 20 + j], m1[j * 8 + k], a);
        qb[t] = fmaxf(a, 0.f);
    }
    __syncthreads();
    if (t < 8) {
        float m = 0.f, v = 0.f;
        for (int r = 0; r < 20; ++r) { float q = qb[r * 8 + t]; m += q; v += q * q; }
        m *= (1.f / 20.f); v = v * (1.f / 20.f) - m * m;
        const float s = g3[t] * rsqrtf(v + BN_EPS);
        sc[t] = s; sh[t] = bt3[t] - m * s;
    }
    __syncthreads();
    if (t < 160) hb[t] = fmaf(qb[t], sc[k], sh[k]);
    __syncthreads();
    if (t < 160) {
        float a = 0.f;
        for (int j = 0; j < 8; ++j) a = fmaf(hb[p * 8 + j], We2[j * 8 + k], a);
        m1[t] = a;
    }
    __syncthreads();
    if (t < 160) {
        float a = be2[k];
        for (int j = 0; j < 20; ++j) a = fmaf(a_g[p * 20 + j], m1[j * 8 + k], a);
        qb[t] = a;
    }
    __syncthreads();
    if (t < 8) {
        float a = 0.f;
        for (int r = 0; r < 20; ++r) a += qb[r * 8 + t];
        out[t] = a;
    }
}

extern "C" void kernel_launch(void* const* d_in, const int* in_sizes, int n_in,
                              void* d_out, int out_size, void* d_ws, size_t ws_size,
                              hipStream_t stream)
{
    const float* x   = (const float*)d_in[0];
    const float* adj = (const float*)d_in[1];
    const float* W1  = (const float*)d_in[2];
    const float* b1  = (const float*)d_in[3];
    const float* W2  = (const float*)d_in[4];
    const float* b2  = (const float*)d_in[5];
    const float* We1 = (const float*)d_in[6];
    const float* be1 = (const float*)d_in[7];
    const float* Wp1 = (const float*)d_in[8];
    const float* bp1 = (const float*)d_in[9];
    const float* W3  = (const float*)d_in[10];
    const float* b3  = (const float*)d_in[11];
    const float* We2 = (const float*)d_in[12];
    const float* be2 = (const float*)d_in[13];
    const float* g1  = (const float*)d_in[14];
    const float* bt1 = (const float*)d_in[15];
    const float* g2  = (const float*)d_in[16];
    const float* bt2 = (const float*)d_in[17];
    const float* g3  = (const float*)d_in[18];
    const float* bt3 = (const float*)d_in[19];

    float* ws = (float*)d_ws;
    float* P  = ws + OFF_P;
    unsigned short* YP   = (unsigned short*)(ws + OFF_YP);
    unsigned short* SLP  = (unsigned short*)(ws + OFF_SLP);
    float* SL  = ws + OFF_SL;
    float* ST1 = ws + OFF_ST1;
    float* ST2 = ws + OFF_ST2;
    float* HSM = ws + OFF_HSM;
    float* AG  = ws + OFF_AG;
    unsigned int* CTR = (unsigned int*)(ws + OFF_CTR);
    unsigned short* ADJP = (unsigned short*)(ws + OFF_ADJB);
    float* out = (float*)d_out;

    const bool FULL = ws_size >= NEED_FULL_BYTES;
    const dim3 blk(256);

    // ---- pass 1 (fused with convert): u1 = relu(adj @ (x@W1) + b1) ----
    // k_y1_pack block 0 zeroes ST1/ST2/HSM/AG/CTR (no memset dispatch).
    k_y1_pack<<<32, blk, 0, stream>>>(x, W1, YP, ST1);
    if (FULL) {
        k_conv_spmm<<<1024, blk, 0, stream>>>(adj, ADJP, YP, P);
        k_red_bn<16, 16, 0, 1><<<64, blk, 0, stream>>>(P, b1, g1, bt1, W2, nullptr, YP, ST1, CTR);

        // ---- pass 2: spmm + BN fused (CTR[1] 512-spin, CTR[2] 64-spin) ----
        k_spmm_bn<<<512, blk, 0, stream>>>(ADJP, YP, P, b2, g2, bt2, We1, Wp1, ST2, CTR + 1);

        // ---- pass 3: spmm + softmax/hsm fused ----
        k_spmm_fin3<<<512, blk, 0, stream>>>(ADJP, YP, P, be1, bp1, SL, SLP, HSM, CTR + 3);

        // ---- pass 4: spmm + a-matrix fused ----
        k_spmm_fin4<<<512, blk, 0, stream>>>(ADJP, SLP, P, SL, AG, CTR + 4);
    } else {
        k_spmm_f32<1, 16><<<1024, blk, 0, stream>>>(adj, YP, P);
        k_red_bn<16, 16, 0, 1><<<64, blk, 0, stream>>>(P, b1, g1, bt1, W2, nullptr, YP, ST1, CTR);

        k_spmm_f32<1, 16><<<1024, blk, 0, stream>>>(adj, YP, P);
        k_red_bn<16, 8, 20, 2><<<64, blk, 0, stream>>>(P, b2, g2, bt2, We1, Wp1, YP, ST2, CTR + 1);

        k_spmm_f32<2, 28><<<1024, blk, 0, stream>>>(adj, YP, P);
        k_red_fin3<16><<<32, blk, 0, stream>>>(P, be1, bp1, SL, SLP, HSM);

        k_spmm_f32<2, 20><<<1024, blk, 0, stream>>>(adj, SLP, P);
        k_red_fin4<16><<<32, blk, 0, stream>>>(P, SL, AG);
    }

    // ---- tiny final stage ----
    k_final<<<1, blk, 0, stream>>>(HSM, AG, W3, b3, g3, bt3, We2, be2, out);
}

// Round 13
// 205.885 us; speedup vs baseline: 1.9506x; 1.9506x over previous
//
#include <hip/hip_runtime.h>
#include <cstddef>

#define NROWS 8192
constexpr float BN_EPS = 1e-5f;

typedef __attribute__((ext_vector_type(8))) short bf16x8;
typedef __attribute__((ext_vector_type(4))) float f32x4;
typedef __attribute__((ext_vector_type(2))) float f32x2;
typedef __attribute__((ext_vector_type(2))) unsigned int u32x2;
typedef __attribute__((ext_vector_type(4))) unsigned int u32x4;

__device__ __forceinline__ unsigned short bf16u(float f) {
    unsigned u = __float_as_uint(f);
    u += 0x7FFFu + ((u >> 16) & 1u);
    return (unsigned short)(u >> 16);
}
__device__ __forceinline__ unsigned bf16pk(float x, float y) {
    return (unsigned)bf16u(x) | ((unsigned)bf16u(y) << 16);
}

// ---- workspace layout (float offsets) ----
constexpr size_t OFF_P   = 0;                                   // 16*8192*32 max
constexpr size_t OFF_YP  = OFF_P   + (size_t)16 * NROWS * 32;   // 8192*32 ushort
constexpr size_t OFF_SLP = OFF_YP  + (size_t)NROWS * 32 / 2;    // 8192*32 ushort
constexpr size_t OFF_U   = OFF_SLP + (size_t)NROWS * 32 / 2;    // (unused)
constexpr size_t OFF_SL  = OFF_U   + (size_t)NROWS * 16;        // 8192*20 f32
constexpr size_t OFF_ST1 = OFF_SL  + (size_t)NROWS * 20;        // 32
constexpr size_t OFF_ST2 = OFF_ST1 + 32;                        // 32
constexpr size_t OFF_HSM = OFF_ST2 + 32;                        // 160
constexpr size_t OFF_AG  = OFF_HSM + 160;                       // 400
constexpr size_t OFF_CTR = OFF_AG  + 400;                       // 8 uint
constexpr int    NSMALL  = 32 + 32 + 160 + 400 + 8;             // 632 floats
constexpr size_t OFF_END_SMALL = OFF_CTR + 8;
constexpr size_t OFF_ADJB = (OFF_END_SMALL + 15) & ~(size_t)15; // 8192*8192 bf16 (packed)
constexpr size_t NEED_FULL_BYTES = (OFF_ADJB + (size_t)NROWS * NROWS / 2) * 4;

// ============================================================
// Packed-fragment ADJP layout, in 16-B units (8 bf16):
//   unit = ((kc*64 + rb)*4 + wv)*2048 + s*128 + m*64 + lane
// lane = rA + 16*khi holds adj[rb*128+wv*32+m*16+rA, kc*512+s*32+khi*8 ..+7]
// LDS swizzle involution: u ^= ((u>>4)&3) ^ (((u>>7)&1)<<2)
// r12 lesson: spin-fusing spmm+reducer in one kernel forces cross-XCD
// P visibility on the critical path (+200 µs) — kernel boundaries stay.
// ============================================================

// ---- fused: fp32 adj -> packed bf16 ADJP AND pass-1 spmm ----
// Single 32 KB LDS buffer (5 blocks/CU). r8 dbuf / r10 subtile pipeline /
// r12 spin-fusion all regressed — plain loop, f32x4 staging.
__global__ __launch_bounds__(256, 4)
void k_conv_spmm(const float* __restrict__ adjf, unsigned short* __restrict__ adjp,
                 const unsigned short* __restrict__ ypu, float* __restrict__ P)
{
    __shared__ unsigned short lds[16384];   // 32 KB = 2048 16-B units
    const int bid = blockIdx.x;
    const int rb = bid & 63, kc = bid >> 6;
    const int t = threadIdx.x, lane = t & 63, wv = t >> 6;
    const int row0 = rb * 128 + wv * 32;
    // f32x4 staging coords: lane covers 4 consecutive k of one row;
    // 2 rows per instruction (srow = lane>>5), 16 iterations cover 32 rows.
    const int srow = lane >> 5;
    const int k4   = (lane & 31) * 4;      // k_local within 128-k quarter
    const int s_q  = (lane >> 3) & 3;      // k4>>5
    const int khi  = (lane >> 1) & 3;      // (k4&31)>>3
    const int el4  = (lane & 1) * 4;       // (k4&31)&7
    const bf16x8* ap = (const bf16x8*)lds;
    const bf16x8* yp = (const bf16x8*)ypu;
    const size_t blockbase = (size_t)(kc * 64 + rb) * 8192;   // 16-B units

    f32x4 acc0 = (f32x4){0.f,0.f,0.f,0.f}, acc1 = (f32x4){0.f,0.f,0.f,0.f};

    for (int q = 0; q < 4; ++q) {
        const int kbase = kc * 512 + q * 128;
        __syncthreads();   // protect LDS from previous iteration's readers
#pragma unroll 16
        for (int rr = 0; rr < 16; ++rr) {
            const int rl = rr * 2 + srow;
            const f32x4 v = *(const f32x4*)(adjf + (size_t)(row0 + rl) * NROWS + kbase + k4);
            const int m = rl >> 4, rA = rl & 15;
            int u = ((wv * 4 + s_q) * 2 + m) * 64 + rA + 16 * khi;
            u ^= ((u >> 4) & 3) ^ (((u >> 7) & 1) << 2);   // bank swizzle
            u32x2 w;
            w.x = bf16pk(v.x, v.y);
            w.y = bf16pk(v.z, v.w);
            *(u32x2*)&lds[u * 8 + el4] = w;                // single 8-B store
        }
        __syncthreads();
        // drain LDS -> packed ADJP (coalesced 4 KB bursts)
#pragma unroll
        for (int i = 0; i < 8; ++i) {
            const int flat = i * 256 + t;
            const int phys = flat ^ ((flat >> 4) & 3) ^ (((flat >> 7) & 1) << 2);
            const u32x4 d = *(const u32x4*)&lds[phys * 8];
            const int wvd = flat >> 9;
            const size_t gu = blockbase + (size_t)wvd * 2048 + (size_t)q * 512 + (flat & 511);
            *(u32x4*)(adjp + gu * 8) = d;
        }
        // MFMA on this q-subtile (A-fragments straight from LDS)
#pragma unroll
        for (int sq = 0; sq < 4; ++sq) {
            int L0 = ((wv * 4 + sq) * 2 + 0) * 64 + lane;
            int L1 = L0 + 64;
            L0 ^= ((L0 >> 4) & 3) ^ (((L0 >> 7) & 1) << 2);
            L1 ^= ((L1 >> 4) & 3) ^ (((L1 >> 7) & 1) << 2);
            const bf16x8 a0 = ap[L0];
            const bf16x8 a1 = ap[L1];
            const bf16x8 b0 = yp[((size_t)(kc * 16 + q * 4 + sq)) * 64 + lane];
            acc0 = __builtin_amdgcn_mfma_f32_16x16x32_bf16(a0, b0, acc0, 0, 0, 0);
            acc1 = __builtin_amdgcn_mfma_f32_16x16x32_bf16(a1, b0, acc1, 0, 0, 0);
        }
    }

    // epilogue: D layout col=lane&15, row=(lane>>4)*4+reg  [m89]
    float* Pk = P + ((size_t)kc * NROWS + row0) * 16;
    const int drow = (lane >> 4) * 4;
    const int dcol = lane & 15;
#pragma unroll
    for (int r = 0; r < 4; ++r) {
        Pk[(size_t)(drow + r) * 16 + dcol]      = acc0[r];
        Pk[(size_t)(16 + drow + r) * 16 + dcol] = acc1[r];
    }
}

// ---- packed-read streaming MFMA spmm, split-k 8 (2 ADJP chunks per block) ----
template<int NT, int CO>
__global__ __launch_bounds__(256)
void k_spmm_p(const unsigned short* __restrict__ adjp,
              const unsigned short* __restrict__ ypu, float* __restrict__ P)
{
    constexpr int CP = NT * 16;
    const int rb   = blockIdx.x & 63;
    const int kc2  = blockIdx.x >> 6;   // 0..7
    const int lane = threadIdx.x & 63;
    const int wv   = threadIdx.x >> 6;
    const int row0 = rb * 128 + wv * 32;
    const bf16x8* ap = (const bf16x8*)adjp;
    const bf16x8* yp = (const bf16x8*)ypu;
    const size_t wbase0 = ((size_t)((kc2 * 2 + 0) * 64 + rb) * 4 + wv) * 2048;
    const size_t wbase1 = ((size_t)((kc2 * 2 + 1) * 64 + rb) * 4 + wv) * 2048;

    f32x4 acc[2][NT];
#pragma unroll
    for (int m = 0; m < 2; ++m)
#pragma unroll
        for (int n = 0; n < NT; ++n) acc[m][n] = (f32x4){0.f, 0.f, 0.f, 0.f};

    auto LA = [&](int m, int s) -> bf16x8 {
        const size_t wb = (s < 16) ? wbase0 : wbase1;
        return ap[wb + (size_t)(s & 15) * 128 + m * 64 + lane];
    };
    auto LB = [&](int n, int s) -> bf16x8 {
        return yp[((size_t)((kc2 * 32 + s) * NT + n)) * 64 + lane];
    };

    bf16x8 a0 = LA(0, 0), a1 = LA(1, 0);
    bf16x8 b0 = LB(0, 0), b1;
    if constexpr (NT == 2) b1 = LB(1, 0);

#pragma unroll
    for (int s = 0; s < 32; ++s) {
        bf16x8 na0, na1, nb0, nb1;
        if (s < 31) {
            na0 = LA(0, s + 1); na1 = LA(1, s + 1);
            nb0 = LB(0, s + 1);
            if constexpr (NT == 2) nb1 = LB(1, s + 1);
        }
        acc[0][0] = __builtin_amdgcn_mfma_f32_16x16x32_bf16(a0, b0, acc[0][0], 0, 0, 0);
        acc[1][0] = __builtin_amdgcn_mfma_f32_16x16x32_bf16(a1, b0, acc[1][0], 0, 0, 0);
        if constexpr (NT == 2) {
            acc[0][1] = __builtin_amdgcn_mfma_f32_16x16x32_bf16(a0, b1, acc[0][1], 0, 0, 0);
            acc[1][1] = __builtin_amdgcn_mfma_f32_16x16x32_bf16(a1, b1, acc[1][1], 0, 0, 0);
        }
        if (s < 31) { a0 = na0; a1 = na1; b0 = nb0; if constexpr (NT == 2) b1 = nb1; }
    }

    float* Pk = P + ((size_t)kc2 * NROWS + row0) * CP;
    const int drow = (lane >> 4) * 4;
    const int dcol = lane & 15;
#pragma unroll
    for (int m = 0; m < 2; ++m)
#pragma unroll
        for (int n = 0; n < NT; ++n)
            if (n * 16 + 0 < CO)
#pragma unroll
                for (int r = 0; r < 4; ++r)
                    if (n * 16 + dcol < CO)
                        Pk[(size_t)(m * 16 + drow + r) * CP + n * 16 + dcol] = acc[m][n][r];
}

// ---- fallback spmm reading fp32 adj directly (non-FULL only, split-16) ----
template<int NT, int CO>
__global__ __launch_bounds__(256)
void k_spmm_f32(const float* __restrict__ adjf,
                const unsigned short* __restrict__ ypu, float* __restrict__ P)
{
    constexpr int CP = NT * 16;
    const int rb   = blockIdx.x & 63;
    const int kc   = blockIdx.x >> 6;
    const int lane = threadIdx.x & 63;
    const int wv   = threadIdx.x >> 6;
    const int row0 = rb * 128 + wv * 32;
    const int k0   = kc * 512;
    const int rA   = lane & 15;
    const int kA   = (lane >> 4) * 8;
    const bf16x8* yp = (const bf16x8*)ypu;

    f32x4 acc[2][NT];
#pragma unroll
    for (int m = 0; m < 2; ++m)
#pragma unroll
        for (int n = 0; n < NT; ++n) acc[m][n] = (f32x4){0.f, 0.f, 0.f, 0.f};

    const size_t offA0 = (size_t)(row0 + rA) * NROWS + k0 + kA;
    const size_t offA1 = offA0 + (size_t)16 * NROWS;

    auto LA = [&](int m, int s) -> bf16x8 {
        const size_t o = (m ? offA1 : offA0) + (size_t)s * 32;
        const f32x4 u = *(const f32x4*)(adjf + o);
        const f32x4 v = *(const f32x4*)(adjf + o + 4);
        bf16x8 tt;
        tt[0] = (short)bf16u(u.x); tt[1] = (short)bf16u(u.y);
        tt[2] = (short)bf16u(u.z); tt[3] = (short)bf16u(u.w);
        tt[4] = (short)bf16u(v.x); tt[5] = (short)bf16u(v.y);
        tt[6] = (short)bf16u(v.z); tt[7] = (short)bf16u(v.w);
        return tt;
    };
    auto LB = [&](int n, int s) -> bf16x8 {
        return yp[((size_t)((kc * 16 + s) * NT + n)) * 64 + lane];
    };

    bf16x8 a0 = LA(0, 0), a1 = LA(1, 0);
    bf16x8 b0 = LB(0, 0), b1;
    if constexpr (NT == 2) b1 = LB(1, 0);

#pragma unroll
    for (int s = 0; s < 16; ++s) {
        bf16x8 na0, na1, nb0, nb1;
        if (s < 15) {
            na0 = LA(0, s + 1); na1 = LA(1, s + 1);
            nb0 = LB(0, s + 1);
            if constexpr (NT == 2) nb1 = LB(1, s + 1);
        }
        acc[0][0] = __builtin_amdgcn_mfma_f32_16x16x32_bf16(a0, b0, acc[0][0], 0, 0, 0);
        acc[1][0] = __builtin_amdgcn_mfma_f32_16x16x32_bf16(a1, b0, acc[1][0], 0, 0, 0);
        if constexpr (NT == 2) {
            acc[0][1] = __builtin_amdgcn_mfma_f32_16x16x32_bf16(a0, b1, acc[0][1], 0, 0, 0);
            acc[1][1] = __builtin_amdgcn_mfma_f32_16x16x32_bf16(a1, b1, acc[1][1], 0, 0, 0);
        }
        if (s < 15) { a0 = na0; a1 = na1; b0 = nb0; if constexpr (NT == 2) b1 = nb1; }
    }

    float* Pk = P + ((size_t)kc * NROWS + row0) * CP;
    const int drow = (lane >> 4) * 4;
    const int dcol = lane & 15;
#pragma unroll
    for (int m = 0; m < 2; ++m)
#pragma unroll
        for (int n = 0; n < NT; ++n)
            if (n * 16 + 0 < CO)
#pragma unroll
                for (int r = 0; r < 4; ++r)
                    if (n * 16 + dcol < CO)
                        Pk[(size_t)(m * 16 + drow + r) * CP + n * 16 + dcol] = acc[m][n][r];
}

// ---- y1 = x @ W1 (packed B-frag) + zero small accumulators (block 0) ----
__global__ __launch_bounds__(256)
void k_y1_pack(const float* __restrict__ x, const float* __restrict__ W1,
               unsigned short* __restrict__ yp, float* __restrict__ zsmall)
{
    if (blockIdx.x == 0) {
        for (int i = threadIdx.x; i < NSMALL; i += 256) zsmall[i] = 0.f;
    }
    const int j = blockIdx.x * 256 + threadIdx.x;
    float xr[18];
#pragma unroll
    for (int d = 0; d < 18; ++d) xr[d] = x[j * 18 + d];
    const int kb = j >> 5, lhi = ((j & 31) >> 3) << 4, idx = j & 7;
#pragma unroll
    for (int c = 0; c < 16; ++c) {
        float a = 0.f;
#pragma unroll
        for (int d = 0; d < 18; ++d) a = fmaf(xr[d], W1[d * 16 + c], a);
        yp[((size_t)kb * 64 + (lhi | c)) * 8 + idx] = bf16u(a);
    }
}

// ---- merged: sum KCN partials + bias + relu (regs) -> BN stats -> grid spin
//      -> BN apply -> y = h@[Wa|Wb] -> packed B-frag bf16. Grid MUST be 64. ----
template<int KCN, int COA, int COB, int NTO>
__global__ __launch_bounds__(256)
void k_red_bn(const float* __restrict__ P, const float* __restrict__ bias,
              const float* __restrict__ g, const float* __restrict__ bt,
              const float* __restrict__ Wa, const float* __restrict__ Wb,
              unsigned short* __restrict__ yp, float* __restrict__ stats,
              unsigned int* __restrict__ ctr)
{
    const int t = threadIdx.x, col = t & 15, rg = t >> 4;
    const int rbase = blockIdx.x * 128;
    float u[8];
    float s = 0.f, ss = 0.f;
#pragma unroll
    for (int i = 0; i < 8; ++i) {
        const int r = rbase + rg + i * 16;
        float v = bias[col];
#pragma unroll
        for (int kc = 0; kc < KCN; ++kc)
            v += P[((size_t)kc * NROWS + r) * 16 + col];
        v = fmaxf(v, 0.f);
        u[i] = v; s += v; ss += v * v;
    }
    __shared__ float ls[16][17], lss[16][17];
    __shared__ float hb[128][17];
    __shared__ float scb[16], shb[16];
    ls[rg][col] = s; lss[rg][col] = ss;
    __syncthreads();
    if (t < 16) {
        float a = 0.f, b = 0.f;
        for (int gg = 0; gg < 16; ++gg) { a += ls[gg][t]; b += lss[gg][t]; }
        atomicAdd(&stats[t], a);
        atomicAdd(&stats[16 + t], b);
    }
    __syncthreads();
    if (t == 0) {
        __threadfence();
        atomicAdd(ctr, 1u);
        while (__hip_atomic_load(ctr, __ATOMIC_RELAXED, __HIP_MEMORY_SCOPE_AGENT) < 64u) {}
        __threadfence();
    }
    __syncthreads();
    if (t < 16) {
        const float sm  = atomicAdd(&stats[t], 0.f);
        const float sq  = atomicAdd(&stats[16 + t], 0.f);
        const float m   = sm * (1.f / NROWS);
        const float var = sq * (1.f / NROWS) - m * m;
        const float sc  = g[t] * rsqrtf(var + BN_EPS);
        scb[t] = sc; shb[t] = bt[t] - m * sc;
    }
    __syncthreads();
#pragma unroll
    for (int i = 0; i < 8; ++i)
        hb[rg + i * 16][col] = fmaf(u[i], scb[col], shb[col]);
    __syncthreads();
    constexpr int CO = COA + COB;
    const int lrow = t >> 1;
    const int jrow = rbase + lrow;
    const int kb = jrow >> 5, lhi = ((jrow & 31) >> 3) << 4, idx = jrow & 7;
    auto slot = [&](int c) -> size_t {
        return ((size_t)(kb * NTO + (c >> 4)) * 64 + (lhi | (c & 15))) * 8 + idx;
    };
    float h[16];
#pragma unroll
    for (int k = 0; k < 16; ++k) h[k] = hb[lrow][k];
    const int c0 = (t & 1) * ((NTO * 16) / 2);
#pragma unroll
    for (int cc = 0; cc < (NTO * 16) / 2; ++cc) {
        const int c = c0 + cc;
        float a = 0.f;
        if (c < COA) {
#pragma unroll
            for (int k = 0; k < 16; ++k) a = fmaf(h[k], Wa[k * COA + c], a);
        } else if (c < CO) {
#pragma unroll
            for (int k = 0; k < 16; ++k) a = fmaf(h[k], Wb[k * COB + (c - COA)], a);
        }
        yp[slot(c)] = (c < CO) ? bf16u(a) : (unsigned short)0;
    }
}

// ---- fused: per-row reduce P(CP=32, 28 cols) + bias; z, softmax -> s_l;
//      write SL f32 + packed bf16; hsm += s_l^T z ----
template<int KCN>
__global__ __launch_bounds__(256)
void k_red_fin3(const float* __restrict__ P, const float* __restrict__ be1,
                const float* __restrict__ bp1, float* __restrict__ sl,
                unsigned short* __restrict__ slp, float* __restrict__ hsm)
{
    __shared__ float szl[256 * 8];
    __shared__ float ssl[256 * 20];
    const int t = threadIdx.x;
    const int row = blockIdx.x * 256 + t;

    float s3[28];
#pragma unroll
    for (int c = 0; c < 28; ++c) s3[c] = 0.f;
#pragma unroll
    for (int kc = 0; kc < KCN; ++kc) {
        const float* pr = &P[((size_t)kc * NROWS + row) * 32];
#pragma unroll
        for (int q = 0; q < 7; ++q) {
            const f32x4 v = *(const f32x4*)(pr + q * 4);
            s3[q * 4 + 0] += v.x; s3[q * 4 + 1] += v.y;
            s3[q * 4 + 2] += v.z; s3[q * 4 + 3] += v.w;
        }
    }
#pragma unroll
    for (int k = 0; k < 8; ++k) szl[t * 8 + k] = s3[k] + be1[k];

    float s[20];
    float mx = -1e30f;
#pragma unroll
    for (int k = 0; k < 20; ++k) {
        s[k] = s3[8 + k] + bp1[k];
        mx = fmaxf(mx, s[k]);
    }
    float se = 0.f;
#pragma unroll
    for (int k = 0; k < 20; ++k) { s[k] = expf(s[k] - mx); se += s[k]; }
    const float inv = 1.f / se;
    const int kb = row >> 5, lhi = ((row & 31) >> 3) << 4, idx = row & 7;
    auto slot = [&](int c) -> size_t {
        return ((size_t)(kb * 2 + (c >> 4)) * 64 + (lhi | (c & 15))) * 8 + idx;
    };
#pragma unroll
    for (int k = 0; k < 20; ++k) {
        s[k] *= inv;
        sl[(size_t)row * 20 + k] = s[k];
        ssl[t * 20 + k] = s[k];
        slp[slot(k)] = bf16u(s[k]);
    }
#pragma unroll
    for (int c = 20; c < 32; ++c) slp[slot(c)] = 0;
    __syncthreads();
    if (t < 160) {
        const int p = t >> 3, q = t & 7;
        float a = 0.f;
        for (int r = 0; r < 256; ++r) a = fmaf(ssl[r * 20 + p], szl[r * 8 + q], a);
        atomicAdd(&hsm[t], a);
    }
}

// ---- fused: per-row reduce P(CP=32, 20 cols); a[p,q] += sum_r sl[r,p]*T4[r,q] ----
template<int KCN>
__global__ __launch_bounds__(256)
void k_red_fin4(const float* __restrict__ P, const float* __restrict__ sl,
                float* __restrict__ a_g)
{
    __shared__ float stt[256 * 20];
    __shared__ float ssl[256 * 20];
    const int t = threadIdx.x;
    const int row = blockIdx.x * 256 + t;

    float t4[20];
#pragma unroll
    for (int c = 0; c < 20; ++c) t4[c] = 0.f;
#pragma unroll
    for (int kc = 0; kc < KCN; ++kc) {
        const float* pr = &P[((size_t)kc * NROWS + row) * 32];
#pragma unroll
        for (int q = 0; q < 5; ++q) {
            const f32x4 v = *(const f32x4*)(pr + q * 4);
            t4[q * 4 + 0] += v.x; t4[q * 4 + 1] += v.y;
            t4[q * 4 + 2] += v.z; t4[q * 4 + 3] += v.w;
        }
    }
#pragma unroll
    for (int c = 0; c < 20; ++c) {
        stt[t * 20 + c] = t4[c];
        ssl[t * 20 + c] = sl[(size_t)row * 20 + c];
    }
    __syncthreads();
    for (int pair = t; pair < 400; pair += 256) {
        const int p = pair / 20, q = pair % 20;
        float a = 0.f;
        for (int r = 0; r < 256; ++r) a = fmaf(ssl[r * 20 + p], stt[r * 20 + q], a);
        atomicAdd(&a_g[pair], a);
    }
}

// ---- tiny final stage ----
__global__ __launch_bounds__(256)
void k_final(const float* __restrict__ hsm, const float* __restrict__ a_g,
             const float* __restrict__ W3, const float* __restrict__ b3,
             const float* __restrict__ g3, const float* __restrict__ bt3,
             const float* __restrict__ We2, const float* __restrict__ be2,
             float* __restrict__ out)
{
    __shared__ float m1[160], qb[160], hb[160], sc[8], sh[8];
    const int t = threadIdx.x;
    const int p = t >> 3, k = t & 7;
    if (t < 160) {
        float a = 0.f;
        for (int j = 0; j < 8; ++j) a = fmaf(hsm[p * 8 + j], W3[j * 8 + k], a);
        m1[t] = a;
    }
    __syncthreads();
    if (t < 160) {
        float a = b3[k];
        for (int j = 0; j < 20; ++j) a = fmaf(a_g[p * 20 + j], m1[j * 8 + k], a);
        qb[t] = fmaxf(a, 0.f);
    }
    __syncthreads();
    if (t < 8) {
        float m = 0.f, v = 0.f;
        for (int r = 0; r < 20; ++r) { float q = qb[r * 8 + t]; m += q; v += q * q; }
        m *= (1.f / 20.f); v = v * (1.f / 20.f) - m * m;
        const float s = g3[t] * rsqrtf(v + BN_EPS);
        sc[t] = s; sh[t] = bt3[t] - m * s;
    }
    __syncthreads();
    if (t < 160) hb[t] = fmaf(qb[t], sc[k], sh[k]);
    __syncthreads();
    if (t < 160) {
        float a = 0.f;
        for (int j = 0; j < 8; ++j) a = fmaf(hb[p * 8 + j], We2[j * 8 + k], a);
        m1[t] = a;
    }
    __syncthreads();
    if (t < 160) {
        float a = be2[k];
        for (int j = 0; j < 20; ++j) a = fmaf(a_g[p * 20 + j], m1[j * 8 + k], a);
        qb[t] = a;
    }
    __syncthreads();
    if (t < 8) {
        float a = 0.f;
        for (int r = 0; r < 20; ++r) a += qb[r * 8 + t];
        out[t] = a;
    }
}

extern "C" void kernel_launch(void* const* d_in, const int* in_sizes, int n_in,
                              void* d_out, int out_size, void* d_ws, size_t ws_size,
                              hipStream_t stream)
{
    const float* x   = (const float*)d_in[0];
    const float* adj = (const float*)d_in[1];
    const float* W1  = (const float*)d_in[2];
    const float* b1  = (const float*)d_in[3];
    const float* W2  = (const float*)d_in[4];
    const float* b2  = (const float*)d_in[5];
    const float* We1 = (const float*)d_in[6];
    const float* be1 = (const float*)d_in[7];
    const float* Wp1 = (const float*)d_in[8];
    const float* bp1 = (const float*)d_in[9];
    const float* W3  = (const float*)d_in[10];
    const float* b3  = (const float*)d_in[11];
    const float* We2 = (const float*)d_in[12];
    const float* be2 = (const float*)d_in[13];
    const float* g1  = (const float*)d_in[14];
    const float* bt1 = (const float*)d_in[15];
    const float* g2  = (const float*)d_in[16];
    const float* bt2 = (const float*)d_in[17];
    const float* g3  = (const float*)d_in[18];
    const float* bt3 = (const float*)d_in[19];

    float* ws = (float*)d_ws;
    float* P  = ws + OFF_P;
    unsigned short* YP   = (unsigned short*)(ws + OFF_YP);
    unsigned short* SLP  = (unsigned short*)(ws + OFF_SLP);
    float* SL  = ws + OFF_SL;
    float* ST1 = ws + OFF_ST1;
    float* ST2 = ws + OFF_ST2;
    float* HSM = ws + OFF_HSM;
    float* AG  = ws + OFF_AG;
    unsigned int* CTR = (unsigned int*)(ws + OFF_CTR);
    unsigned short* ADJP = (unsigned short*)(ws + OFF_ADJB);
    float* out = (float*)d_out;

    const bool FULL = ws_size >= NEED_FULL_BYTES;
    const dim3 blk(256);

    // ---- pass 1 (fused with convert): u1 = relu(adj @ (x@W1) + b1) ----
    // k_y1_pack block 0 zeroes ST1/ST2/HSM/AG/CTR (no memset dispatch).
    k_y1_pack<<<32, blk, 0, stream>>>(x, W1, YP, ST1);
    if (FULL) {
        k_conv_spmm<<<1024, blk, 0, stream>>>(adj, ADJP, YP, P);
        k_red_bn<16, 16, 0, 1><<<64, blk, 0, stream>>>(P, b1, g1, bt1, W2, nullptr, YP, ST1, CTR);

        // ---- pass 2 ----
        k_spmm_p<1, 16><<<512, blk, 0, stream>>>(ADJP, YP, P);
        k_red_bn<8, 8, 20, 2><<<64, blk, 0, stream>>>(P, b2, g2, bt2, We1, Wp1, YP, ST2, CTR + 1);

        // ---- pass 3 ----
        k_spmm_p<2, 28><<<512, blk, 0, stream>>>(ADJP, YP, P);
        k_red_fin3<8><<<32, blk, 0, stream>>>(P, be1, bp1, SL, SLP, HSM);

        // ---- pass 4 ----
        k_spmm_p<2, 20><<<512, blk, 0, stream>>>(ADJP, SLP, P);
        k_red_fin4<8><<<32, blk, 0, stream>>>(P, SL, AG);
    } else {
        k_spmm_f32<1, 16><<<1024, blk, 0, stream>>>(adj, YP, P);
        k_red_bn<16, 16, 0, 1><<<64, blk, 0, stream>>>(P, b1, g1, bt1, W2, nullptr, YP, ST1, CTR);

        k_spmm_f32<1, 16><<<1024, blk, 0, stream>>>(adj, YP, P);
        k_red_bn<16, 8, 20, 2><<<64, blk, 0, stream>>>(P, b2, g2, bt2, We1, Wp1, YP, ST2, CTR + 1);

        k_spmm_f32<2, 28><<<1024, blk, 0, stream>>>(adj, YP, P);
        k_red_fin3<16><<<32, blk, 0, stream>>>(P, be1, bp1, SL, SLP, HSM);

        k_spmm_f32<2, 20><<<1024, blk, 0, stream>>>(adj, SLP, P);
        k_red_fin4<16><<<32, blk, 0, stream>>>(P, SL, AG);
    }

    // ---- tiny final stage ----
    k_final<<<1, blk, 0, stream>>>(HSM, AG, W3, b3, g3, bt3, We2, be2, out);
}

// Round 14
// 197.697 us; speedup vs baseline: 2.0314x; 1.0414x over previous
//
#include <hip/hip_runtime.h>
#include <cstddef>

#define NROWS 8192
constexpr float BN_EPS = 1e-5f;

typedef __attribute__((ext_vector_type(8))) short bf16x8;
typedef __attribute__((ext_vector_type(4))) float f32x4;
typedef __attribute__((ext_vector_type(2))) float f32x2;
typedef __attribute__((ext_vector_type(4))) unsigned int u32x4;

__device__ __forceinline__ unsigned short bf16u(float f) {
    unsigned u = __float_as_uint(f);
    u += 0x7FFFu + ((u >> 16) & 1u);
    return (unsigned short)(u >> 16);
}
__device__ __forceinline__ unsigned bf16pk(float x, float y) {
    return (unsigned)bf16u(x) | ((unsigned)bf16u(y) << 16);
}

// ---- workspace layout (float offsets) ----
constexpr size_t OFF_P   = 0;                                   // 16*8192*32 max
constexpr size_t OFF_YP  = OFF_P   + (size_t)16 * NROWS * 32;   // 8192*32 ushort
constexpr size_t OFF_SLP = OFF_YP  + (size_t)NROWS * 32 / 2;    // 8192*32 ushort
constexpr size_t OFF_U   = OFF_SLP + (size_t)NROWS * 32 / 2;    // (unused)
constexpr size_t OFF_SL  = OFF_U   + (size_t)NROWS * 16;        // 8192*20 f32
constexpr size_t OFF_ST1 = OFF_SL  + (size_t)NROWS * 20;        // 32
constexpr size_t OFF_ST2 = OFF_ST1 + 32;                        // 32
constexpr size_t OFF_HSM = OFF_ST2 + 32;                        // 160
constexpr size_t OFF_AG  = OFF_HSM + 160;                       // 400
constexpr size_t OFF_CTR = OFF_AG  + 400;                       // 8 uint
constexpr int    NSMALL  = 32 + 32 + 160 + 400 + 8;             // 632 floats
constexpr size_t OFF_END_SMALL = OFF_CTR + 8;
constexpr size_t OFF_ADJB = (OFF_END_SMALL + 15) & ~(size_t)15; // 8192*8192 bf16 (packed)
constexpr size_t NEED_FULL_BYTES = (OFF_ADJB + (size_t)NROWS * NROWS / 2) * 4;

// ============================================================
// Packed-fragment ADJP layout, in 16-B units (8 bf16):
//   unit = ((kc*64 + rb)*4 + wv)*2048 + s*128 + m*64 + lane
// lane = rA + 16*khi holds adj[rb*128+wv*32+m*16+rA, kc*512+s*32+khi*8 ..+7]
// LDS swizzle involution: u ^= ((u>>4)&3) ^ (((u>>7)&1)<<2)
// Failed-experiment ledger (keep for future reference):
//  r8  64KB LDS dbuf        -> occupancy cliff (2 blk/CU), +100 µs
//  r10 16KB subtile pipeline -> narrow bursts + VGPR tax, +10 µs
//  r4  nontemporal hints     -> defeats cache allocation, +65 µs
//  r12 spin-fused reducers   -> cross-XCD P flush on critical path, +204 µs
//  r13 f32x4 staging         -> paired-lane LDS writes, less MLP, +8 µs
// ============================================================

// ---- fused: fp32 adj -> packed bf16 ADJP AND pass-1 spmm ----
// Single 32 KB LDS buffer (5 blocks/CU), plain barrier loop — best measured.
__global__ __launch_bounds__(256)
void k_conv_spmm(const float* __restrict__ adjf, unsigned short* __restrict__ adjp,
                 const unsigned short* __restrict__ ypu, float* __restrict__ P)
{
    __shared__ unsigned short lds[16384];   // 32 KB = 2048 16-B units
    const int bid = blockIdx.x;
    const int rb = bid & 63, kc = bid >> 6;
    const int t = threadIdx.x, lane = t & 63, wv = t >> 6;
    const int row0 = rb * 128 + wv * 32;
    const int s_q = lane >> 4;             // s within quarter (0..3)
    const int khi = (lane >> 2) & 3;       // 8-elem group within 32-k step
    const int el2 = (lane & 3) * 2;        // elem pair base within 8 (even)
    const bf16x8* ap = (const bf16x8*)lds;
    const bf16x8* yp = (const bf16x8*)ypu;
    const size_t blockbase = (size_t)(kc * 64 + rb) * 8192;   // 16-B units

    f32x4 acc0 = (f32x4){0.f,0.f,0.f,0.f}, acc1 = (f32x4){0.f,0.f,0.f,0.f};

    for (int q = 0; q < 4; ++q) {
        const int kbase = kc * 512 + q * 128;
        __syncthreads();   // protect LDS from previous iteration's readers
#pragma unroll 8
        for (int rr = 0; rr < 32; ++rr) {
            const f32x2 v = *(const f32x2*)(adjf + (size_t)(row0 + rr) * NROWS + kbase + lane * 2);
            const int m = rr >> 4, rA = rr & 15;
            int u = ((wv * 4 + s_q) * 2 + m) * 64 + rA + 16 * khi;
            u ^= ((u >> 4) & 3) ^ (((u >> 7) & 1) << 2);   // bank swizzle
            *(unsigned*)&lds[u * 8 + el2] = bf16pk(v.x, v.y);  // packed u32 write
        }
        __syncthreads();
        // drain LDS -> packed ADJP (coalesced 4 KB bursts)
#pragma unroll
        for (int i = 0; i < 8; ++i) {
            const int flat = i * 256 + t;
            const int phys = flat ^ ((flat >> 4) & 3) ^ (((flat >> 7) & 1) << 2);
            const u32x4 d = *(const u32x4*)&lds[phys * 8];
            const int wvd = flat >> 9;
            const size_t gu = blockbase + (size_t)wvd * 2048 + (size_t)q * 512 + (flat & 511);
            *(u32x4*)(adjp + gu * 8) = d;
        }
        // MFMA on this q-subtile (A-fragments straight from LDS)
#pragma unroll
        for (int sq = 0; sq < 4; ++sq) {
            int L0 = ((wv * 4 + sq) * 2 + 0) * 64 + lane;
            int L1 = L0 + 64;
            L0 ^= ((L0 >> 4) & 3) ^ (((L0 >> 7) & 1) << 2);
            L1 ^= ((L1 >> 4) & 3) ^ (((L1 >> 7) & 1) << 2);
            const bf16x8 a0 = ap[L0];
            const bf16x8 a1 = ap[L1];
            const bf16x8 b0 = yp[((size_t)(kc * 16 + q * 4 + sq)) * 64 + lane];
            acc0 = __builtin_amdgcn_mfma_f32_16x16x32_bf16(a0, b0, acc0, 0, 0, 0);
            acc1 = __builtin_amdgcn_mfma_f32_16x16x32_bf16(a1, b0, acc1, 0, 0, 0);
        }
    }

    // epilogue: D layout col=lane&15, row=(lane>>4)*4+reg  [m89]
    float* Pk = P + ((size_t)kc * NROWS + row0) * 16;
    const int drow = (lane >> 4) * 4;
    const int dcol = lane & 15;
#pragma unroll
    for (int r = 0; r < 4; ++r) {
        Pk[(size_t)(drow + r) * 16 + dcol]      = acc0[r];
        Pk[(size_t)(16 + drow + r) * 16 + dcol] = acc1[r];
    }
}

// ---- packed-read streaming MFMA spmm, split-k 8 (2 ADJP chunks per block) ----
template<int NT, int CO>
__global__ __launch_bounds__(256)
void k_spmm_p(const unsigned short* __restrict__ adjp,
              const unsigned short* __restrict__ ypu, float* __restrict__ P)
{
    constexpr int CP = NT * 16;
    const int rb   = blockIdx.x & 63;
    const int kc2  = blockIdx.x >> 6;   // 0..7
    const int lane = threadIdx.x & 63;
    const int wv   = threadIdx.x >> 6;
    const int row0 = rb * 128 + wv * 32;
    const bf16x8* ap = (const bf16x8*)adjp;
    const bf16x8* yp = (const bf16x8*)ypu;
    const size_t wbase0 = ((size_t)((kc2 * 2 + 0) * 64 + rb) * 4 + wv) * 2048;
    const size_t wbase1 = ((size_t)((kc2 * 2 + 1) * 64 + rb) * 4 + wv) * 2048;

    f32x4 acc[2][NT];
#pragma unroll
    for (int m = 0; m < 2; ++m)
#pragma unroll
        for (int n = 0; n < NT; ++n) acc[m][n] = (f32x4){0.f, 0.f, 0.f, 0.f};

    auto LA = [&](int m, int s) -> bf16x8 {
        const size_t wb = (s < 16) ? wbase0 : wbase1;
        return ap[wb + (size_t)(s & 15) * 128 + m * 64 + lane];
    };
    auto LB = [&](int n, int s) -> bf16x8 {
        return yp[((size_t)((kc2 * 32 + s) * NT + n)) * 64 + lane];
    };

    bf16x8 a0 = LA(0, 0), a1 = LA(1, 0);
    bf16x8 b0 = LB(0, 0), b1;
    if constexpr (NT == 2) b1 = LB(1, 0);

#pragma unroll
    for (int s = 0; s < 32; ++s) {
        bf16x8 na0, na1, nb0, nb1;
        if (s < 31) {
            na0 = LA(0, s + 1); na1 = LA(1, s + 1);
            nb0 = LB(0, s + 1);
            if constexpr (NT == 2) nb1 = LB(1, s + 1);
        }
        acc[0][0] = __builtin_amdgcn_mfma_f32_16x16x32_bf16(a0, b0, acc[0][0], 0, 0, 0);
        acc[1][0] = __builtin_amdgcn_mfma_f32_16x16x32_bf16(a1, b0, acc[1][0], 0, 0, 0);
        if constexpr (NT == 2) {
            acc[0][1] = __builtin_amdgcn_mfma_f32_16x16x32_bf16(a0, b1, acc[0][1], 0, 0, 0);
            acc[1][1] = __builtin_amdgcn_mfma_f32_16x16x32_bf16(a1, b1, acc[1][1], 0, 0, 0);
        }
        if (s < 31) { a0 = na0; a1 = na1; b0 = nb0; if constexpr (NT == 2) b1 = nb1; }
    }

    float* Pk = P + ((size_t)kc2 * NROWS + row0) * CP;
    const int drow = (lane >> 4) * 4;
    const int dcol = lane & 15;
#pragma unroll
    for (int m = 0; m < 2; ++m)
#pragma unroll
        for (int n = 0; n < NT; ++n)
            if (n * 16 + 0 < CO)
#pragma unroll
                for (int r = 0; r < 4; ++r)
                    if (n * 16 + dcol < CO)
                        Pk[(size_t)(m * 16 + drow + r) * CP + n * 16 + dcol] = acc[m][n][r];
}

// ---- fallback spmm reading fp32 adj directly (non-FULL only, split-16) ----
template<int NT, int CO>
__global__ __launch_bounds__(256)
void k_spmm_f32(const float* __restrict__ adjf,
                const unsigned short* __restrict__ ypu, float* __restrict__ P)
{
    constexpr int CP = NT * 16;
    const int rb   = blockIdx.x & 63;
    const int kc   = blockIdx.x >> 6;
    const int lane = threadIdx.x & 63;
    const int wv   = threadIdx.x >> 6;
    const int row0 = rb * 128 + wv * 32;
    const int k0   = kc * 512;
    const int rA   = lane & 15;
    const int kA   = (lane >> 4) * 8;
    const bf16x8* yp = (const bf16x8*)ypu;

    f32x4 acc[2][NT];
#pragma unroll
    for (int m = 0; m < 2; ++m)
#pragma unroll
        for (int n = 0; n < NT; ++n) acc[m][n] = (f32x4){0.f, 0.f, 0.f, 0.f};

    const size_t offA0 = (size_t)(row0 + rA) * NROWS + k0 + kA;
    const size_t offA1 = offA0 + (size_t)16 * NROWS;

    auto LA = [&](int m, int s) -> bf16x8 {
        const size_t o = (m ? offA1 : offA0) + (size_t)s * 32;
        const f32x4 u = *(const f32x4*)(adjf + o);
        const f32x4 v = *(const f32x4*)(adjf + o + 4);
        bf16x8 tt;
        tt[0] = (short)bf16u(u.x); tt[1] = (short)bf16u(u.y);
        tt[2] = (short)bf16u(u.z); tt[3] = (short)bf16u(u.w);
        tt[4] = (short)bf16u(v.x); tt[5] = (short)bf16u(v.y);
        tt[6] = (short)bf16u(v.z); tt[7] = (short)bf16u(v.w);
        return tt;
    };
    auto LB = [&](int n, int s) -> bf16x8 {
        return yp[((size_t)((kc * 16 + s) * NT + n)) * 64 + lane];
    };

    bf16x8 a0 = LA(0, 0), a1 = LA(1, 0);
    bf16x8 b0 = LB(0, 0), b1;
    if constexpr (NT == 2) b1 = LB(1, 0);

#pragma unroll
    for (int s = 0; s < 16; ++s) {
        bf16x8 na0, na1, nb0, nb1;
        if (s < 15) {
            na0 = LA(0, s + 1); na1 = LA(1, s + 1);
            nb0 = LB(0, s + 1);
            if constexpr (NT == 2) nb1 = LB(1, s + 1);
        }
        acc[0][0] = __builtin_amdgcn_mfma_f32_16x16x32_bf16(a0, b0, acc[0][0], 0, 0, 0);
        acc[1][0] = __builtin_amdgcn_mfma_f32_16x16x32_bf16(a1, b0, acc[1][0], 0, 0, 0);
        if constexpr (NT == 2) {
            acc[0][1] = __builtin_amdgcn_mfma_f32_16x16x32_bf16(a0, b1, acc[0][1], 0, 0, 0);
            acc[1][1] = __builtin_amdgcn_mfma_f32_16x16x32_bf16(a1, b1, acc[1][1], 0, 0, 0);
        }
        if (s < 15) { a0 = na0; a1 = na1; b0 = nb0; if constexpr (NT == 2) b1 = nb1; }
    }

    float* Pk = P + ((size_t)kc * NROWS + row0) * CP;
    const int drow = (lane >> 4) * 4;
    const int dcol = lane & 15;
#pragma unroll
    for (int m = 0; m < 2; ++m)
#pragma unroll
        for (int n = 0; n < NT; ++n)
            if (n * 16 + 0 < CO)
#pragma unroll
                for (int r = 0; r < 4; ++r)
                    if (n * 16 + dcol < CO)
                        Pk[(size_t)(m * 16 + drow + r) * CP + n * 16 + dcol] = acc[m][n][r];
}

// ---- y1 = x @ W1 (packed B-frag) + zero small accumulators (block 0) ----
__global__ __launch_bounds__(256)
void k_y1_pack(const float* __restrict__ x, const float* __restrict__ W1,
               unsigned short* __restrict__ yp, float* __restrict__ zsmall)
{
    if (blockIdx.x == 0) {
        for (int i = threadIdx.x; i < NSMALL; i += 256) zsmall[i] = 0.f;
    }
    const int j = blockIdx.x * 256 + threadIdx.x;
    float xr[18];
#pragma unroll
    for (int d = 0; d < 18; ++d) xr[d] = x[j * 18 + d];
    const int kb = j >> 5, lhi = ((j & 31) >> 3) << 4, idx = j & 7;
#pragma unroll
    for (int c = 0; c < 16; ++c) {
        float a = 0.f;
#pragma unroll
        for (int d = 0; d < 18; ++d) a = fmaf(xr[d], W1[d * 16 + c], a);
        yp[((size_t)kb * 64 + (lhi | c)) * 8 + idx] = bf16u(a);
    }
}

// ---- merged: sum KCN partials + bias + relu (regs) -> BN stats -> grid spin
//      -> BN apply -> y = h@[Wa|Wb] -> packed B-frag bf16. Grid MUST be 64. ----
template<int KCN, int COA, int COB, int NTO>
__global__ __launch_bounds__(256)
void k_red_bn(const float* __restrict__ P, const float* __restrict__ bias,
              const float* __restrict__ g, const float* __restrict__ bt,
              const float* __restrict__ Wa, const float* __restrict__ Wb,
              unsigned short* __restrict__ yp, float* __restrict__ stats,
              unsigned int* __restrict__ ctr)
{
    const int t = threadIdx.x, col = t & 15, rg = t >> 4;
    const int rbase = blockIdx.x * 128;
    float u[8];
    float s = 0.f, ss = 0.f;
#pragma unroll
    for (int i = 0; i < 8; ++i) {
        const int r = rbase + rg + i * 16;
        float v = bias[col];
#pragma unroll
        for (int kc = 0; kc < KCN; ++kc)
            v += P[((size_t)kc * NROWS + r) * 16 + col];
        v = fmaxf(v, 0.f);
        u[i] = v; s += v; ss += v * v;
    }
    __shared__ float ls[16][17], lss[16][17];
    __shared__ float hb[128][17];
    __shared__ float scb[16], shb[16];
    ls[rg][col] = s; lss[rg][col] = ss;
    __syncthreads();
    if (t < 16) {
        float a = 0.f, b = 0.f;
        for (int gg = 0; gg < 16; ++gg) { a += ls[gg][t]; b += lss[gg][t]; }
        atomicAdd(&stats[t], a);
        atomicAdd(&stats[16 + t], b);
    }
    __syncthreads();
    if (t == 0) {
        __threadfence();
        atomicAdd(ctr, 1u);
        while (__hip_atomic_load(ctr, __ATOMIC_RELAXED, __HIP_MEMORY_SCOPE_AGENT) < 64u) {}
        __threadfence();
    }
    __syncthreads();
    if (t < 16) {
        const float sm  = atomicAdd(&stats[t], 0.f);
        const float sq  = atomicAdd(&stats[16 + t], 0.f);
        const float m   = sm * (1.f / NROWS);
        const float var = sq * (1.f / NROWS) - m * m;
        const float sc  = g[t] * rsqrtf(var + BN_EPS);
        scb[t] = sc; shb[t] = bt[t] - m * sc;
    }
    __syncthreads();
#pragma unroll
    for (int i = 0; i < 8; ++i)
        hb[rg + i * 16][col] = fmaf(u[i], scb[col], shb[col]);
    __syncthreads();
    constexpr int CO = COA + COB;
    const int lrow = t >> 1;
    const int jrow = rbase + lrow;
    const int kb = jrow >> 5, lhi = ((jrow & 31) >> 3) << 4, idx = jrow & 7;
    auto slot = [&](int c) -> size_t {
        return ((size_t)(kb * NTO + (c >> 4)) * 64 + (lhi | (c & 15))) * 8 + idx;
    };
    float h[16];
#pragma unroll
    for (int k = 0; k < 16; ++k) h[k] = hb[lrow][k];
    const int c0 = (t & 1) * ((NTO * 16) / 2);
#pragma unroll
    for (int cc = 0; cc < (NTO * 16) / 2; ++cc) {
        const int c = c0 + cc;
        float a = 0.f;
        if (c < COA) {
#pragma unroll
            for (int k = 0; k < 16; ++k) a = fmaf(h[k], Wa[k * COA + c], a);
        } else if (c < CO) {
#pragma unroll
            for (int k = 0; k < 16; ++k) a = fmaf(h[k], Wb[k * COB + (c - COA)], a);
        }
        yp[slot(c)] = (c < CO) ? bf16u(a) : (unsigned short)0;
    }
}

// ---- fused: per-row reduce P(CP=32, 28 cols) + bias; z, softmax -> s_l;
//      write SL f32 + packed bf16; hsm += s_l^T z ----
template<int KCN>
__global__ __launch_bounds__(256)
void k_red_fin3(const float* __restrict__ P, const float* __restrict__ be1,
                const float* __restrict__ bp1, float* __restrict__ sl,
                unsigned short* __restrict__ slp, float* __restrict__ hsm)
{
    __shared__ float szl[256 * 8];
    __shared__ float ssl[256 * 20];
    const int t = threadIdx.x;
    const int row = blockIdx.x * 256 + t;

    float s3[28];
#pragma unroll
    for (int c = 0; c < 28; ++c) s3[c] = 0.f;
#pragma unroll
    for (int kc = 0; kc < KCN; ++kc) {
        const float* pr = &P[((size_t)kc * NROWS + row) * 32];
#pragma unroll
        for (int q = 0; q < 7; ++q) {
            const f32x4 v = *(const f32x4*)(pr + q * 4);
            s3[q * 4 + 0] += v.x; s3[q * 4 + 1] += v.y;
            s3[q * 4 + 2] += v.z; s3[q * 4 + 3] += v.w;
        }
    }
#pragma unroll
    for (int k = 0; k < 8; ++k) szl[t * 8 + k] = s3[k] + be1[k];

    float s[20];
    float mx = -1e30f;
#pragma unroll
    for (int k = 0; k < 20; ++k) {
        s[k] = s3[8 + k] + bp1[k];
        mx = fmaxf(mx, s[k]);
    }
    float se = 0.f;
#pragma unroll
    for (int k = 0; k < 20; ++k) { s[k] = expf(s[k] - mx); se += s[k]; }
    const float inv = 1.f / se;
    const int kb = row >> 5, lhi = ((row & 31) >> 3) << 4, idx = row & 7;
    auto slot = [&](int c) -> size_t {
        return ((size_t)(kb * 2 + (c >> 4)) * 64 + (lhi | (c & 15))) * 8 + idx;
    };
#pragma unroll
    for (int k = 0; k < 20; ++k) {
        s[k] *= inv;
        sl[(size_t)row * 20 + k] = s[k];
        ssl[t * 20 + k] = s[k];
        slp[slot(k)] = bf16u(s[k]);
    }
#pragma unroll
    for (int c = 20; c < 32; ++c) slp[slot(c)] = 0;
    __syncthreads();
    if (t < 160) {
        const int p = t >> 3, q = t & 7;
        float a = 0.f;
        for (int r = 0; r < 256; ++r) a = fmaf(ssl[r * 20 + p], szl[r * 8 + q], a);
        atomicAdd(&hsm[t], a);
    }
}

// ---- fused: per-row reduce P(CP=32, 20 cols); a[p,q] += sum_r sl[r,p]*T4[r,q] ----
template<int KCN>
__global__ __launch_bounds__(256)
void k_red_fin4(const float* __restrict__ P, const float* __restrict__ sl,
                float* __restrict__ a_g)
{
    __shared__ float stt[256 * 20];
    __shared__ float ssl[256 * 20];
    const int t = threadIdx.x;
    const int row = blockIdx.x * 256 + t;

    float t4[20];
#pragma unroll
    for (int c = 0; c < 20; ++c) t4[c] = 0.f;
#pragma unroll
    for (int kc = 0; kc < KCN; ++kc) {
        const float* pr = &P[((size_t)kc * NROWS + row) * 32];
#pragma unroll
        for (int q = 0; q < 5; ++q) {
            const f32x4 v = *(const f32x4*)(pr + q * 4);
            t4[q * 4 + 0] += v.x; t4[q * 4 + 1] += v.y;
            t4[q * 4 + 2] += v.z; t4[q * 4 + 3] += v.w;
        }
    }
#pragma unroll
    for (int c = 0; c < 20; ++c) {
        stt[t * 20 + c] = t4[c];
        ssl[t * 20 + c] = sl[(size_t)row * 20 + c];
    }
    __syncthreads();
    for (int pair = t; pair < 400; pair += 256) {
        const int p = pair / 20, q = pair % 20;
        float a = 0.f;
        for (int r = 0; r < 256; ++r) a = fmaf(ssl[r * 20 + p], stt[r * 20 + q], a);
        atomicAdd(&a_g[pair], a);
    }
}

// ---- tiny final stage ----
__global__ __launch_bounds__(256)
void k_final(const float* __restrict__ hsm, const float* __restrict__ a_g,
             const float* __restrict__ W3, const float* __restrict__ b3,
             const float* __restrict__ g3, const float* __restrict__ bt3,
             const float* __restrict__ We2, const float* __restrict__ be2,
             float* __restrict__ out)
{
    __shared__ float m1[160], qb[160], hb[160], sc[8], sh[8];
    const int t = threadIdx.x;
    const int p = t >> 3, k = t & 7;
    if (t < 160) {
        float a = 0.f;
        for (int j = 0; j < 8; ++j) a = fmaf(hsm[p * 8 + j], W3[j * 8 + k], a);
        m1[t] = a;
    }
    __syncthreads();
    if (t < 160) {
        float a = b3[k];
        for (int j = 0; j < 20; ++j) a = fmaf(a_g[p * 20 + j], m1[j * 8 + k], a);
        qb[t] = fmaxf(a, 0.f);
    }
    __syncthreads();
    if (t < 8) {
        float m = 0.f, v = 0.f;
        for (int r = 0; r < 20; ++r) { float q = qb[r * 8 + t]; m += q; v += q * q; }
        m *= (1.f / 20.f); v = v * (1.f / 20.f) - m * m;
        const float s = g3[t] * rsqrtf(v + BN_EPS);
        sc[t] = s; sh[t] = bt3[t] - m * s;
    }
    __syncthreads();
    if (t < 160) hb[t] = fmaf(qb[t], sc[k], sh[k]);
    __syncthreads();
    if (t < 160) {
        float a = 0.f;
        for (int j = 0; j < 8; ++j) a = fmaf(hb[p * 8 + j], We2[j * 8 + k], a);
        m1[t] = a;
    }
    __syncthreads();
    if (t < 160) {
        float a = be2[k];
        for (int j = 0; j < 20; ++j) a = fmaf(a_g[p * 20 + j], m1[j * 8 + k], a);
        qb[t] = a;
    }
    __syncthreads();
    if (t < 8) {
        float a = 0.f;
        for (int r = 0; r < 20; ++r) a += qb[r * 8 + t];
        out[t] = a;
    }
}

extern "C" void kernel_launch(void* const* d_in, const int* in_sizes, int n_in,
                              void* d_out, int out_size, void* d_ws, size_t ws_size,
                              hipStream_t stream)
{
    const float* x   = (const float*)d_in[0];
    const float* adj = (const float*)d_in[1];
    const float* W1  = (const float*)d_in[2];
    const float* b1  = (const float*)d_in[3];
    const float* W2  = (const float*)d_in[4];
    const float* b2  = (const float*)d_in[5];
    const float* We1 = (const float*)d_in[6];
    const float* be1 = (const float*)d_in[7];
    const float* Wp1 = (const float*)d_in[8];
    const float* bp1 = (const float*)d_in[9];
    const float* W3  = (const float*)d_in[10];
    const float* b3  = (const float*)d_in[11];
    const float* We2 = (const float*)d_in[12];
    const float* be2 = (const float*)d_in[13];
    const float* g1  = (const float*)d_in[14];
    const float* bt1 = (const float*)d_in[15];
    const float* g2  = (const float*)d_in[16];
    const float* bt2 = (const float*)d_in[17];
    const float* g3  = (const float*)d_in[18];
    const float* bt3 = (const float*)d_in[19];

    float* ws = (float*)d_ws;
    float* P  = ws + OFF_P;
    unsigned short* YP   = (unsigned short*)(ws + OFF_YP);
    unsigned short* SLP  = (unsigned short*)(ws + OFF_SLP);
    float* SL  = ws + OFF_SL;
    float* ST1 = ws + OFF_ST1;
    float* ST2 = ws + OFF_ST2;
    float* HSM = ws + OFF_HSM;
    float* AG  = ws + OFF_AG;
    unsigned int* CTR = (unsigned int*)(ws + OFF_CTR);
    unsigned short* ADJP = (unsigned short*)(ws + OFF_ADJB);
    float* out = (float*)d_out;

    const bool FULL = ws_size >= NEED_FULL_BYTES;
    const dim3 blk(256);

    // ---- pass 1 (fused with convert): u1 = relu(adj @ (x@W1) + b1) ----
    // k_y1_pack block 0 zeroes ST1/ST2/HSM/AG/CTR (no memset dispatch).
    k_y1_pack<<<32, blk, 0, stream>>>(x, W1, YP, ST1);
    if (FULL) {
        k_conv_spmm<<<1024, blk, 0, stream>>>(adj, ADJP, YP, P);
        k_red_bn<16, 16, 0, 1><<<64, blk, 0, stream>>>(P, b1, g1, bt1, W2, nullptr, YP, ST1, CTR);

        // ---- pass 2 ----
        k_spmm_p<1, 16><<<512, blk, 0, stream>>>(ADJP, YP, P);
        k_red_bn<8, 8, 20, 2><<<64, blk, 0, stream>>>(P, b2, g2, bt2, We1, Wp1, YP, ST2, CTR + 1);

        // ---- pass 3 ----
        k_spmm_p<2, 28><<<512, blk, 0, stream>>>(ADJP, YP, P);
        k_red_fin3<8><<<32, blk, 0, stream>>>(P, be1, bp1, SL, SLP, HSM);

        // ---- pass 4 ----
        k_spmm_p<2, 20><<<512, blk, 0, stream>>>(ADJP, SLP, P);
        k_red_fin4<8><<<32, blk, 0, stream>>>(P, SL, AG);
    } else {
        k_spmm_f32<1, 16><<<1024, blk, 0, stream>>>(adj, YP, P);
        k_red_bn<16, 16, 0, 1><<<64, blk, 0, stream>>>(P, b1, g1, bt1, W2, nullptr, YP, ST1, CTR);

        k_spmm_f32<1, 16><<<1024, blk, 0, stream>>>(adj, YP, P);
        k_red_bn<16, 8, 20, 2><<<64, blk, 0, stream>>>(P, b2, g2, bt2, We1, Wp1, YP, ST2, CTR + 1);

        k_spmm_f32<2, 28><<<1024, blk, 0, stream>>>(adj, YP, P);
        k_red_fin3<16><<<32, blk, 0, stream>>>(P, be1, bp1, SL, SLP, HSM);

        k_spmm_f32<2, 20><<<1024, blk, 0, stream>>>(adj, SLP, P);
        k_red_fin4<16><<<32, blk, 0, stream>>>(P, SL, AG);
    }

    // ---- tiny final stage ----
    k_final<<<1, blk, 0, stream>>>(HSM, AG, W3, b3, g3, bt3, We2, be2, out);
}